// Round 8
// baseline (284.772 us; speedup 1.0000x reference)
//
#include <hip/hip_runtime.h>
#include <stdint.h>

// ---------------------------------------------------------------------------
// NonLocalBlock2D  B=16, C=512, I=256, N=3136.  Weight-space factorization:
//   S_b = X X^T (Gram, 512x512), s_b = X·1
//   E = W_w g_w, F^T[ct,c1] = sum_j th_w[j,ct] ph_w[j,c1]   (precomputed)
//   T_b = E·S_b ;  V_b = T_b·F /N + (1/N) ug tps_b^T + ((1/N) w2_b + ug) tp^T
//   c0_b = (1/N)E(S_b pt) + (ptb_b/N) ug + phtb((1/N)w2_b + ug) + W_b
//   out = x + V_b ·NT xb + c0_b
// where ug=W_w g_b, tp=th_w^T ph_b, pt=ph_w^T th_b, pws=ph_w s, w2=E s,
//       tps=th_w^T pws, ptb=pws·th_b, phtb=ph_b·th_b.
// Kernels: prep1 -> EF(gemm) -> pass1(x->xb,xc,spart) -> S(gemm) ->
//          combine -> T(gemm) -> V(gemm) -> final(g1-style + f32 epilogue)
// ---------------------------------------------------------------------------

typedef unsigned short ushort_t;
typedef __attribute__((ext_vector_type(8))) short short8;
typedef __attribute__((ext_vector_type(4))) float f32x4;
typedef __attribute__((ext_vector_type(4))) unsigned short us4;
typedef __attribute__((ext_vector_type(8))) unsigned short us8;

#define NSP  3136
#define XNR  3200

#define AS1(p) ((const __attribute__((address_space(1))) void*)(p))
#define AS3(p) ((__attribute__((address_space(3))) void*)(p))

__device__ inline ushort_t f2b(float f) {
  union { float f; uint32_t u; } c; c.f = f;
  uint32_t u = c.u;
  uint32_t r = (u + 0x7fffu + ((u >> 16) & 1u)) >> 16;
  return (ushort_t)r;
}
__device__ inline float b2f(ushort_t u) {
  union { uint32_t x; float f; } c; c.x = (uint32_t)u << 16; return c.f;
}

// ==================== generic 128^2 NT GEMM (BK=64, swizzled) ================
// MODE 10: EF  : bz0: E = Wwb .NT gwT ; bz1: FT = TwT .NT PwT   (K=256, bf16)
// MODE 11: S   : Sf[b] = xc[b] .NT xc[b]  (K=3136, f32 out)
// MODE 12: T   : T[b] = E .NT Sb[b]       (K=512, bf16)
// MODE 13: V   : V[b] = T[b] .NT FT /N + rank-1 terms  (K=512, bf16)
template<int MODE>
__global__ __launch_bounds__(256, 2) void gemm64(
    const ushort_t* __restrict__ Abase,
    const ushort_t* __restrict__ Bbase,
    void* __restrict__ Cbase, void* __restrict__ C2,
    const float* __restrict__ v_ug, const float* __restrict__ v_tp,
    const float* __restrict__ v_w2, const float* __restrict__ v_tps)
{
  constexpr int TB = 256;
  constexpr int MR = 4;
  constexpr int CH = TB / 8;

  const int nwg = gridDim.x * gridDim.y * gridDim.z;
  int flat = blockIdx.x + gridDim.x * (blockIdx.y + gridDim.y * blockIdx.z);
  const int q = nwg >> 3;
  int swz = (flat & 7) * q + (flat >> 3);
  const int bx = swz % gridDim.x; int tmp = swz / gridDim.x;
  const int by = tmp % gridDim.y;
  const int bz = tmp / gridDim.y;

  int b = bz, kbeg = 0, kend, lda, ldb;
  const ushort_t *A, *B;
  if constexpr (MODE == 10) {
    A = Abase + (size_t)bz * 131072;   // Wwb | TwT
    B = Bbase + (size_t)bz * 131072;   // gwT | PwT
    lda = 256; ldb = 256; kend = 256;
  } else if constexpr (MODE == 11) {
    A = Abase + (size_t)b * 512 * NSP;
    B = A;
    lda = NSP; ldb = NSP; kend = NSP;
  } else if constexpr (MODE == 12) {
    A = Abase;                          // E
    B = Bbase + (size_t)b * 262144;     // Sb
    lda = 512; ldb = 512; kend = 512;
  } else {
    A = Abase + (size_t)b * 262144;     // T
    B = Bbase;                          // FT
    lda = 512; ldb = 512; kend = 512;
  }

  const int m0 = bx * 128;
  const int n0 = by * 128;
  const int tid = threadIdx.x;
  const int lane = tid & 63;
  const int wid = tid >> 6;
  const int wm = wid >> 1, wn = wid & 1;
  const int fr = lane & 15;
  const int fk = lane >> 4;

  __shared__ __align__(16) ushort_t As[2][128 * 64];
  __shared__ __align__(16) ushort_t Bs[2][128 * 64];

  f32x4 acc[MR][4];
#pragma unroll
  for (int i = 0; i < MR; ++i)
#pragma unroll
    for (int j = 0; j < 4; ++j) acc[i][j] = f32x4{0.f, 0.f, 0.f, 0.f};

  const int srow = tid >> 3;
  const int lsl = (tid & 7) ^ (srow & 7);
  const ushort_t* pa = A + (size_t)(m0 + srow) * lda + kbeg + lsl * 8;
  const ushort_t* pb = B + (size_t)(n0 + srow) * ldb + kbeg + lsl * 8;

#define STAGE(bufi) do {                                                              \
    __builtin_amdgcn_global_load_lds(AS1(pa),                    AS3(&As[bufi][tid * 8]), 16, 0, 0); \
    __builtin_amdgcn_global_load_lds(AS1(pa + (size_t)CH * lda), AS3(&As[bufi][TB * 8 + tid * 8]), 16, 0, 0); \
    __builtin_amdgcn_global_load_lds(AS1(pa + (size_t)2 * CH * lda), AS3(&As[bufi][2 * TB * 8 + tid * 8]), 16, 0, 0); \
    __builtin_amdgcn_global_load_lds(AS1(pa + (size_t)3 * CH * lda), AS3(&As[bufi][3 * TB * 8 + tid * 8]), 16, 0, 0); \
    __builtin_amdgcn_global_load_lds(AS1(pb),                    AS3(&Bs[bufi][tid * 8]), 16, 0, 0); \
    __builtin_amdgcn_global_load_lds(AS1(pb + (size_t)CH * ldb), AS3(&Bs[bufi][TB * 8 + tid * 8]), 16, 0, 0); \
    __builtin_amdgcn_global_load_lds(AS1(pb + (size_t)2 * CH * ldb), AS3(&Bs[bufi][2 * TB * 8 + tid * 8]), 16, 0, 0); \
    __builtin_amdgcn_global_load_lds(AS1(pb + (size_t)3 * CH * ldb), AS3(&Bs[bufi][3 * TB * 8 + tid * 8]), 16, 0, 0); \
    pa += 64; pb += 64;                                                               \
  } while (0)

  const int sw = fr & 7;
  const int s0 = ((0 | fk) ^ sw) * 8;
  const int s1 = ((4 | fk) ^ sw) * 8;
  const int arow = (wm * MR * 16 + fr) * 64;
  const int brow = (wn * 64 + fr) * 64;

  asm volatile("s_waitcnt vmcnt(0)" ::: "memory");
  STAGE(0);

  const int nkt = (kend - kbeg) >> 6;
  for (int t = 0; t < nkt; ++t) {
    const int cur = t & 1;
    if (t + 1 < nkt) {
      STAGE(cur ^ 1);
      asm volatile("s_waitcnt vmcnt(8)" ::: "memory");
    } else {
      asm volatile("s_waitcnt vmcnt(0)" ::: "memory");
    }
    __builtin_amdgcn_s_barrier();
    __builtin_amdgcn_sched_barrier(0);

    short8 bf[4][2];
#pragma unroll
    for (int n = 0; n < 4; ++n) {
      bf[n][0] = *reinterpret_cast<const short8*>(&Bs[cur][brow + n * 1024 + s0]);
      bf[n][1] = *reinterpret_cast<const short8*>(&Bs[cur][brow + n * 1024 + s1]);
    }
    short8 af[4][2];
#pragma unroll
    for (int m = 0; m < 4; ++m) {
      af[m][0] = *reinterpret_cast<const short8*>(&As[cur][arow + m * 1024 + s0]);
      af[m][1] = *reinterpret_cast<const short8*>(&As[cur][arow + m * 1024 + s1]);
    }
    __builtin_amdgcn_s_setprio(1);
#pragma unroll
    for (int m = 0; m < 4; ++m)
#pragma unroll
      for (int n = 0; n < 4; ++n) {
        acc[m][n] = __builtin_amdgcn_mfma_f32_16x16x32_bf16(af[m][0], bf[n][0], acc[m][n], 0, 0, 0);
        acc[m][n] = __builtin_amdgcn_mfma_f32_16x16x32_bf16(af[m][1], bf[n][1], acc[m][n], 0, 0, 0);
      }
    __builtin_amdgcn_s_setprio(0);
    __builtin_amdgcn_s_barrier();
  }
#undef STAGE

  // D: col = fr (+n*16), row = fk*4 + r (+m*16)
  if constexpr (MODE == 10) {
    ushort_t* dst = (bz == 0) ? (ushort_t*)Cbase : (ushort_t*)C2;
#pragma unroll
    for (int m = 0; m < MR; ++m)
#pragma unroll
      for (int n = 0; n < 4; ++n) {
        int gcol = n0 + wn * 64 + n * 16 + fr;
#pragma unroll
        for (int r = 0; r < 4; ++r) {
          int grow = m0 + wm * 64 + m * 16 + fk * 4 + r;
          dst[(size_t)grow * 512 + gcol] = f2b(acc[m][n][r]);
        }
      }
  } else if constexpr (MODE == 11) {
    float* Sf = (float*)Cbase;
#pragma unroll
    for (int m = 0; m < MR; ++m)
#pragma unroll
      for (int n = 0; n < 4; ++n) {
        int gcol = n0 + wn * 64 + n * 16 + fr;
#pragma unroll
        for (int r = 0; r < 4; ++r) {
          int grow = m0 + wm * 64 + m * 16 + fk * 4 + r;
          Sf[(size_t)b * 262144 + (size_t)grow * 512 + gcol] = acc[m][n][r];
        }
      }
  } else if constexpr (MODE == 12) {
    ushort_t* T = (ushort_t*)Cbase;
#pragma unroll
    for (int m = 0; m < MR; ++m)
#pragma unroll
      for (int n = 0; n < 4; ++n) {
        int gcol = n0 + wn * 64 + n * 16 + fr;
#pragma unroll
        for (int r = 0; r < 4; ++r) {
          int grow = m0 + wm * 64 + m * 16 + fk * 4 + r;
          T[(size_t)b * 262144 + (size_t)grow * 512 + gcol] = f2b(acc[m][n][r]);
        }
      }
  } else {
    const float invN = 1.0f / 3136.0f;
    ushort_t* V = (ushort_t*)Cbase;
#pragma unroll
    for (int m = 0; m < MR; ++m)
#pragma unroll
      for (int n = 0; n < 4; ++n) {
        int gcol = n0 + wn * 64 + n * 16 + fr;
        float tpsv = v_tps[b * 512 + gcol];
        float tpv  = v_tp[gcol];
#pragma unroll
        for (int r = 0; r < 4; ++r) {
          int grow = m0 + wm * 64 + m * 16 + fk * 4 + r;
          float ugv = v_ug[grow];
          float w2v = v_w2[b * 512 + grow];
          float val = acc[m][n][r] * invN + ugv * tpsv * invN
                    + (w2v * invN + ugv) * tpv;
          V[(size_t)b * 262144 + (size_t)grow * 512 + gcol] = f2b(val);
        }
      }
  }
}

// ===================== final: out = V .NT xb + x + c0 ======================
__global__ __launch_bounds__(512, 2) void gfinal(
    const ushort_t* __restrict__ Vb,
    const ushort_t* __restrict__ xbase,
    float* __restrict__ out,
    const float* __restrict__ xres,
    const float* __restrict__ c0)
{
  const int nwg = gridDim.x * gridDim.y * gridDim.z;   // 416, %8==0
  int flat = blockIdx.x + gridDim.x * (blockIdx.y + gridDim.y * blockIdx.z);
  const int q = nwg >> 3;
  int swz = (flat & 7) * q + (flat >> 3);
  const int bx = swz % gridDim.x; int tmp = swz / gridDim.x;
  const int by = tmp % gridDim.y;
  const int b  = tmp / gridDim.y;

  const int m0 = bx * 256;
  const int n0 = by * 256;
  const ushort_t* Ag = Vb + (size_t)b * 262144;
  const ushort_t* Bg = xbase + (size_t)b * XNR * 512;

  const int tid = threadIdx.x;
  const int lane = tid & 63;
  const int wid = tid >> 6;
  const int wm = wid >> 2;
  const int wn = wid & 3;
  const int fr = lane & 15;
  const int fk = lane >> 4;
  const int hB = wn >> 1;
  const int rB0 = (wn & 1) * 64;
  const int s0 = ((fk) ^ (fr & 7)) * 8;
  const int s1 = ((4 | fk) ^ (fr & 7)) * 8;
  const int rth = tid >> 3;
  const int swc = ((tid & 7) ^ ((tid >> 3) & 7)) * 8;

  __shared__ __align__(16) ushort_t SM[65536];
  ushort_t (*As)[2][8192] = (ushort_t(*)[2][8192])(SM);
  ushort_t (*Bs)[2][8192] = (ushort_t(*)[2][8192])(SM + 32768);

  f32x4 acc[8][4];
#pragma unroll
  for (int i = 0; i < 8; ++i)
#pragma unroll
    for (int j = 0; j < 4; ++j) acc[i][j] = f32x4{0.f, 0.f, 0.f, 0.f};

#define STG_A(h, kt, BUF) do { \
    const ushort_t* s_ = Ag + (size_t)(m0 + (h) * 128 + rth) * 512 + (kt) * 64 + swc; \
    __builtin_amdgcn_global_load_lds(AS1(s_), AS3(&As[BUF][h][tid * 8]), 16, 0, 0); \
    __builtin_amdgcn_global_load_lds(AS1(s_ + 64 * 512), AS3(&As[BUF][h][4096 + tid * 8]), 16, 0, 0); \
  } while (0)
#define STG_B(h, kt, BUF) do { \
    const ushort_t* s_ = Bg + (size_t)(n0 + (h) * 128 + rth) * 512 + (kt) * 64 + swc; \
    __builtin_amdgcn_global_load_lds(AS1(s_), AS3(&Bs[BUF][h][tid * 8]), 16, 0, 0); \
    __builtin_amdgcn_global_load_lds(AS1(s_ + 64 * 512), AS3(&Bs[BUF][h][4096 + tid * 8]), 16, 0, 0); \
  } while (0)

#define BARR __builtin_amdgcn_s_barrier()
#define LGKM0 do { asm volatile("s_waitcnt lgkmcnt(0)" ::: "memory"); \
                   __builtin_amdgcn_sched_barrier(0); } while (0)
#define MF16(AF, BF, OFS) do { \
    __builtin_amdgcn_s_setprio(1); \
    _Pragma("unroll") for (int mf_ = 0; mf_ < 4; ++mf_) \
    _Pragma("unroll") for (int nf_ = 0; nf_ < 4; ++nf_) \
      acc[(OFS) + mf_][nf_] = __builtin_amdgcn_mfma_f32_16x16x32_bf16( \
          AF[mf_], BF[nf_], acc[(OFS) + mf_][nf_], 0, 0, 0); \
    __builtin_amdgcn_s_setprio(0); \
  } while (0)

#define TILE(T, CUR, DO_B1, DO_T2, VMN) do { \
    short8 a0[4], a1[4], a2[4], a3[4], b0[4], b1[4]; \
    _Pragma("unroll") for (int i = 0; i < 4; ++i) \
      a0[i] = *(const short8*)&As[CUR][wm][(i * 16 + fr) * 64 + s0]; \
    _Pragma("unroll") for (int i = 0; i < 4; ++i) \
      b0[i] = *(const short8*)&Bs[CUR][hB][(rB0 + i * 16 + fr) * 64 + s0]; \
    if (DO_B1) STG_B(1, (T) + 1, (CUR) ^ 1); \
    BARR; LGKM0; MF16(a0, b0, 0); BARR; \
    _Pragma("unroll") for (int i = 0; i < 4; ++i) \
      a1[i] = *(const short8*)&As[CUR][wm][((i + 4) * 16 + fr) * 64 + s0]; \
    _Pragma("unroll") for (int i = 0; i < 4; ++i) \
      b1[i] = *(const short8*)&Bs[CUR][hB][(rB0 + i * 16 + fr) * 64 + s1]; \
    BARR; LGKM0; MF16(a1, b0, 4); BARR; \
    _Pragma("unroll") for (int i = 0; i < 4; ++i) \
      a2[i] = *(const short8*)&As[CUR][wm][(i * 16 + fr) * 64 + s1]; \
    _Pragma("unroll") for (int i = 0; i < 4; ++i) \
      a3[i] = *(const short8*)&As[CUR][wm][((i + 4) * 16 + fr) * 64 + s1]; \
    if (DO_T2) STG_B(0, (T) + 2, (CUR)); \
    BARR; LGKM0; MF16(a2, b1, 0); BARR; \
    if (DO_T2) { STG_A(0, (T) + 2, (CUR)); STG_A(1, (T) + 2, (CUR)); } \
    if ((VMN) == 6) asm volatile("s_waitcnt vmcnt(6)" ::: "memory"); \
    else if ((VMN) == 0) asm volatile("s_waitcnt vmcnt(0)" ::: "memory"); \
    BARR; MF16(a3, b1, 4); BARR; \
  } while (0)

  asm volatile("s_waitcnt vmcnt(0)" ::: "memory");
  STG_A(0, 0, 0); STG_A(1, 0, 0); STG_B(0, 0, 0); STG_B(1, 0, 0);
  STG_B(0, 1, 1); STG_A(0, 1, 1); STG_A(1, 1, 1);
  asm volatile("s_waitcnt vmcnt(6)" ::: "memory");
  BARR;

  for (int t = 0; t < 6; t += 2) { TILE(t, 0, 1, 1, 6); TILE(t + 1, 1, 1, 1, 6); }
  TILE(6, 0, 1, 0, 0);
  TILE(7, 1, 0, 0, -1);

#undef TILE
#undef STG_A
#undef STG_B

  // ===== f32 epilogue via LDS roundtrip: out = acc + x + c0[row] =====
  float* SMf = (float*)SM;          // 128 x 256 f32 = 128 KiB exactly
  const float* c0v = c0 + (size_t)b * 512;
#pragma unroll
  for (int p = 0; p < 2; ++p) {
    if (wm == p) {
#pragma unroll
      for (int m = 0; m < 8; ++m)
#pragma unroll
        for (int n = 0; n < 4; ++n) {
          int col = wn * 64 + n * 16 + fr;
#pragma unroll
          for (int r = 0; r < 4; ++r)
            SMf[(m * 16 + fk * 4 + r) * 256 + col] = acc[m][n][r];
        }
    }
    BARR;
#pragma unroll
    for (int it = 0; it < 16; ++it) {
      int idx = it * 512 + tid;
      int row = idx >> 6, ch = idx & 63;
      int gcol = n0 + ch * 4;
      if (gcol < NSP) {
        int grow = m0 + p * 128 + row;
        size_t o = ((size_t)b * 512 + grow) * (size_t)NSP + gcol;
        f32x4 v = *reinterpret_cast<const f32x4*>(&SMf[row * 256 + ch * 4]);
        f32x4 xr = *reinterpret_cast<const f32x4*>(&xres[o]);
        float bi = c0v[grow];
        f32x4 ov = {v[0] + bi + xr[0], v[1] + bi + xr[1],
                    v[2] + bi + xr[2], v[3] + bi + xr[3]};
        *reinterpret_cast<f32x4*>(&out[o]) = ov;
      }
    }
    BARR;
  }
#undef BARR
#undef LGKM0
#undef MF16
}

// ====== pass1: x[b][512][3136] f32 -> xb[b][3200][512], xc[b][512][3136],
//               spart[b][512][49] (partial row sums) ======
__global__ __launch_bounds__(256) void pass1(const float* __restrict__ x,
                                             ushort_t* __restrict__ xb,
                                             ushort_t* __restrict__ xc,
                                             float* __restrict__ spart)
{
  const int nt = blockIdx.x, ct = blockIdx.y, b = blockIdx.z;
  const int t = threadIdx.x;
  const int n0 = nt * 64, c0 = ct * 64;
  __shared__ float Ls[64 * 65];
  __shared__ float Ps[64][17];

  const float* xs = x + (size_t)b * 512 * NSP;
#pragma unroll
  for (int p = 0; p < 4; ++p) {
    int cl = p * 16 + (t >> 4);
    int nl = (t & 15) * 4;
    f32x4 v = *reinterpret_cast<const f32x4*>(&xs[(size_t)(c0 + cl) * NSP + n0 + nl]);
    Ls[cl * 65 + nl + 0] = v[0];
    Ls[cl * 65 + nl + 1] = v[1];
    Ls[cl * 65 + nl + 2] = v[2];
    Ls[cl * 65 + nl + 3] = v[3];
    us4 o;
    o[0] = f2b(v[0]); o[1] = f2b(v[1]); o[2] = f2b(v[2]); o[3] = f2b(v[3]);
    *reinterpret_cast<us4*>(&xc[((size_t)b * 512 + c0 + cl) * NSP + n0 + nl]) = o;
    Ps[cl][t & 15] = v[0] + v[1] + v[2] + v[3];
  }
  __syncthreads();
  if (t < 64) {
    float a = 0.f;
#pragma unroll
    for (int k = 0; k < 16; ++k) a += Ps[t][k];
    spart[((size_t)b * 512 + c0 + t) * 49 + nt] = a;
  }
#pragma unroll
  for (int it = 0; it < 2; ++it) {
    int idx = it * 256 + t; int nl = idx >> 3, cc = idx & 7;
    us8 o;
#pragma unroll
    for (int j = 0; j < 8; ++j) o[j] = f2b(Ls[(cc * 8 + j) * 65 + nl]);
    *reinterpret_cast<us8*>(&xb[((size_t)b * XNR + n0 + nl) * 512 + c0 + cc * 8]) = o;
  }
}

// ====== prep1: weight cvts/transposes + const vectors ======
__global__ __launch_bounds__(256) void prep1(
    const float* __restrict__ g_w, const float* __restrict__ ph_w,
    const float* __restrict__ th_w, const float* __restrict__ W_w,
    const float* __restrict__ g_b, const float* __restrict__ ph_b,
    const float* __restrict__ th_b,
    ushort_t* __restrict__ Wwb, ushort_t* __restrict__ TwT,
    ushort_t* __restrict__ gwT, ushort_t* __restrict__ PwT,
    float* __restrict__ ug, float* __restrict__ tp, float* __restrict__ pt)
{
  int i = blockIdx.x * 256 + threadIdx.x;
  if (i < 131072) {
    Wwb[i] = f2b(W_w[i]);
  } else if (i < 262144) {
    int j = i - 131072; int ct = j >> 8; int k = j & 255;
    TwT[j] = f2b(th_w[k * 512 + ct]);
  } else if (i < 393216) {
    int j = i - 262144; int c = j >> 8; int k = j & 255;
    gwT[j] = f2b(g_w[k * 512 + c]);
  } else if (i < 524288) {
    int j = i - 393216; int c = j >> 8; int k = j & 255;
    PwT[j] = f2b(ph_w[k * 512 + c]);
  } else if (i < 524800) {
    int c = i - 524288;
    float a = 0.f;
    for (int k = 0; k < 256; ++k) a += W_w[c * 256 + k] * g_b[k];
    ug[c] = a;
  } else if (i < 525312) {
    int c = i - 524800;
    float a = 0.f;
    for (int j = 0; j < 256; ++j) a += th_w[(size_t)j * 512 + c] * ph_b[j];
    tp[c] = a;
  } else if (i < 525824) {
    int c = i - 525312;
    float a = 0.f;
    for (int j = 0; j < 256; ++j) a += ph_w[(size_t)j * 512 + c] * th_b[j];
    pt[c] = a;
  }
}

// ====== combine: per-batch vectors + Sb bf16 ======
__global__ __launch_bounds__(512) void combine(
    const float* __restrict__ Sf, const float* __restrict__ spart,
    const ushort_t* __restrict__ E,
    const float* __restrict__ ph_w, const float* __restrict__ th_w,
    const float* __restrict__ th_b, const float* __restrict__ ph_b,
    const float* __restrict__ pt, const float* __restrict__ ug,
    const float* __restrict__ W_b,
    ushort_t* __restrict__ Sb, float* __restrict__ w2o,
    float* __restrict__ tpso, float* __restrict__ c0o)
{
  const int b = blockIdx.x;
  const int t = threadIdx.x;
  __shared__ float sL[512], svL[512], pwsL[256], red[2];
  const float* S0 = Sf + (size_t)b * 262144;

  float sc = 0.f;
  const float* sp = spart + ((size_t)b * 512 + t) * 49;
  for (int k = 0; k < 49; ++k) sc += sp[k];
  sL[t] = sc;
  __syncthreads();

  if (t < 256) {
    const float* pw = ph_w + (size_t)t * 512;
    float a = 0.f;
    for (int c = 0; c < 512; ++c) a += pw[c] * sL[c];
    pwsL[t] = a;
  }
  {
    // sv[t] = sum_r S[r][t] * pt[r]  (S symmetric -> column form, coalesced)
    float a = 0.f;
    for (int r = 0; r < 512; ++r) a += S0[(size_t)r * 512 + t] * pt[r];
    svL[t] = a;
  }
  __syncthreads();

  if (t == 0) {
    float a = 0.f, p2 = 0.f;
    for (int j = 0; j < 256; ++j) { a += pwsL[j] * th_b[j]; p2 += ph_b[j] * th_b[j]; }
    red[0] = a; red[1] = p2;
  }
  __syncthreads();
  const float ptb = red[0], phtb = red[1];

  float w2a = 0.f, c0a = 0.f;
  const ushort_t* Er = E + (size_t)t * 512;
  for (int c = 0; c < 512; ++c) {
    float e = b2f(Er[c]);
    w2a += e * sL[c];
    c0a += e * svL[c];
  }
  float tpsa = 0.f;
  for (int j = 0; j < 256; ++j) tpsa += th_w[(size_t)j * 512 + t] * pwsL[j];

  const float invN = 1.0f / 3136.0f;
  w2o[b * 512 + t] = w2a;
  tpso[b * 512 + t] = tpsa;
  c0o[b * 512 + t] = c0a * invN + ptb * invN * ug[t]
                   + phtb * (w2a * invN + ug[t]) + W_b[t];

  ushort_t* sb = Sb + (size_t)b * 262144;
  for (int i = 0; i < 512; ++i) {
    int idx = i * 512 + t;
    sb[idx] = f2b(S0[idx]);
  }
}

extern "C" void kernel_launch(void* const* d_in, const int* in_sizes, int n_in,
                              void* d_out, int out_size, void* d_ws, size_t ws_size,
                              hipStream_t stream) {
  const float* x    = (const float*)d_in[0];
  const float* g_w  = (const float*)d_in[1];
  const float* g_b  = (const float*)d_in[2];
  const float* th_w = (const float*)d_in[3];
  const float* th_b = (const float*)d_in[4];
  const float* ph_w = (const float*)d_in[5];
  const float* ph_b = (const float*)d_in[6];
  const float* W_w  = (const float*)d_in[7];
  const float* W_b  = (const float*)d_in[8];

  char* ws = (char*)d_ws;
  ushort_t* xb   = (ushort_t*)(ws + 0);            // 52,428,800
  ushort_t* xc   = (ushort_t*)(ws + 52428800);     // 51,380,224 (dead after S)
  ushort_t* T    = (ushort_t*)(ws + 52428800);     // 8,388,608 (aliases xc)
  ushort_t* V    = (ushort_t*)(ws + 60817408);     // 8,388,608 (aliases xc)
  ushort_t* Sb   = (ushort_t*)(ws + 69206016);     // 8,388,608 (aliases xc)
  float*    Sf   = (float*)(ws + 103809024);       // 16,777,216
  float*    spart= (float*)(ws + 120586240);       // 1,605,632
  ushort_t* E    = (ushort_t*)(ws + 122191872);    // 524,288
  ushort_t* FT   = (ushort_t*)(ws + 122716160);    // 524,288
  ushort_t* Wwb  = (ushort_t*)(ws + 123240448);    // 262,144
  ushort_t* TwT  = (ushort_t*)(ws + 123502592);    // 262,144
  ushort_t* gwT  = (ushort_t*)(ws + 123764736);    // 262,144
  ushort_t* PwT  = (ushort_t*)(ws + 124026880);    // 262,144
  float*    ug   = (float*)(ws + 124289024);       // 2,048
  float*    tp   = (float*)(ws + 124291072);       // 2,048
  float*    pt   = (float*)(ws + 124293120);       // 2,048
  float*    w2   = (float*)(ws + 124295168);       // 32,768
  float*    tps  = (float*)(ws + 124327936);       // 32,768
  float*    c0   = (float*)(ws + 124360704);       // 32,768

  prep1<<<2054, 256, 0, stream>>>(g_w, ph_w, th_w, W_w, g_b, ph_b, th_b,
                                  Wwb, TwT, gwT, PwT, ug, tp, pt);
  // E = Wwb .NT gwT ; FT = TwT .NT PwT
  gemm64<10><<<dim3(4, 4, 2), 256, 0, stream>>>(Wwb, gwT, E, FT,
                                                nullptr, nullptr, nullptr, nullptr);
  pass1<<<dim3(49, 8, 16), 256, 0, stream>>>(x, xb, xc, spart);
  // S_b = xc .NT xc  (K=3136)
  gemm64<11><<<dim3(4, 4, 16), 256, 0, stream>>>(xc, xc, Sf, nullptr,
                                                 nullptr, nullptr, nullptr, nullptr);
  combine<<<16, 512, 0, stream>>>(Sf, spart, E, ph_w, th_w, th_b, ph_b,
                                  pt, ug, W_b, Sb, w2, tps, c0);
  // T_b = E .NT Sb
  gemm64<12><<<dim3(4, 4, 16), 256, 0, stream>>>(E, Sb, T, nullptr,
                                                 nullptr, nullptr, nullptr, nullptr);
  // V_b = T .NT FT /N + rank-1
  gemm64<13><<<dim3(4, 4, 16), 256, 0, stream>>>(T, FT, V, nullptr,
                                                 ug, tp, w2, tps);
  // out = V .NT xb + x + c0
  gfinal<<<dim3(2, 13, 16), 512, 0, stream>>>(V, xb, (float*)d_out, x, c0);
}

// Round 9
// 186.779 us; speedup vs baseline: 1.5246x; 1.5246x over previous
//
#include <hip/hip_runtime.h>
#include <stdint.h>

// ---------------------------------------------------------------------------
// NonLocalBlock2D  B=16, C=512, I=256, N=3136.
// Pipeline (R7 base + Z-factorization of the th projection):
//   xb  [b][3200][512] = x^T bf16 (rows 3136..3199 zeroed)
//   G1 (256^2 8-phase, M=512): P[b][512][3200] = [g_w;ph_w].NT xb + bias (g,ph)
//   G2 (128^2): Mf2 partials = ph .NT g, split-K 5x640
//   cvt: MT2[b][j][i] = (1/N) sum partials
//   GU (128^2): U_b = Ww .NT MT2_b          [512][256]
//   Zg (128^2): Z_b = U_b .NT th_w^T        [512][512]
//   u3: c0[b][c] = sum_j U[b][c][j] th_b[j] + W_b[c]
//   gfinal (256^2 8-phase): out = Z .NT xb + x + c0
// Identity: out = U(th_w X + th_b) = (U th_w) X + (U th_b) 1^T  -> no th rows,
// no thT transpose, G1 drops to 512 rows.
// ---------------------------------------------------------------------------

typedef unsigned short ushort_t;
typedef __attribute__((ext_vector_type(8))) short short8;
typedef __attribute__((ext_vector_type(4))) float f32x4;
typedef __attribute__((ext_vector_type(4))) unsigned short us4;
typedef __attribute__((ext_vector_type(8))) unsigned short us8;

#define NSP  3136
#define XNR  3200
#define PLD  3200

#define AS1(p) ((const __attribute__((address_space(1))) void*)(p))
#define AS3(p) ((__attribute__((address_space(3))) void*)(p))

__device__ inline ushort_t f2b(float f) {
  union { float f; uint32_t u; } c; c.f = f;
  uint32_t u = c.u;
  uint32_t r = (u + 0x7fffu + ((u >> 16) & 1u)) >> 16;
  return (ushort_t)r;
}
__device__ inline float b2f(ushort_t u) {
  union { uint32_t x; float f; } c; c.x = (uint32_t)u << 16; return c.f;
}

// ============================ G1: 8-phase 256^2 ============================
__global__ __launch_bounds__(512, 2) void g1_8phase(
    const ushort_t* __restrict__ W2,
    const ushort_t* __restrict__ xbase,
    ushort_t* __restrict__ P,
    const float* __restrict__ bias)
{
  const int nwg = gridDim.x * gridDim.y * gridDim.z;   // 416, %8==0
  int flat = blockIdx.x + gridDim.x * (blockIdx.y + gridDim.y * blockIdx.z);
  const int q = nwg >> 3;
  int swz = (flat & 7) * q + (flat >> 3);
  const int bx = swz % gridDim.x; int tmp = swz / gridDim.x;
  const int by = tmp % gridDim.y;
  const int b  = tmp / gridDim.y;

  const int m0 = bx * 256;
  const int n0 = by * 256;
  const ushort_t* Ag = W2;
  const ushort_t* Bg = xbase + (size_t)b * XNR * 512;

  const int tid = threadIdx.x;
  const int lane = tid & 63;
  const int wid = tid >> 6;
  const int wm = wid >> 2;
  const int wn = wid & 3;
  const int fr = lane & 15;
  const int fk = lane >> 4;
  const int hB = wn >> 1;
  const int rB0 = (wn & 1) * 64;
  const int s0 = ((fk) ^ (fr & 7)) * 8;
  const int s1 = ((4 | fk) ^ (fr & 7)) * 8;
  const int rth = tid >> 3;
  const int swc = ((tid & 7) ^ ((tid >> 3) & 7)) * 8;

  __shared__ __align__(16) ushort_t SM[65536];
  ushort_t (*As)[2][8192] = (ushort_t(*)[2][8192])(SM);
  ushort_t (*Bs)[2][8192] = (ushort_t(*)[2][8192])(SM + 32768);

  f32x4 acc[8][4];
#pragma unroll
  for (int i = 0; i < 8; ++i)
#pragma unroll
    for (int j = 0; j < 4; ++j) acc[i][j] = f32x4{0.f, 0.f, 0.f, 0.f};

#define STG_A(h, kt, BUF) do { \
    const ushort_t* s_ = Ag + (size_t)(m0 + (h) * 128 + rth) * 512 + (kt) * 64 + swc; \
    __builtin_amdgcn_global_load_lds(AS1(s_), AS3(&As[BUF][h][tid * 8]), 16, 0, 0); \
    __builtin_amdgcn_global_load_lds(AS1(s_ + 64 * 512), AS3(&As[BUF][h][4096 + tid * 8]), 16, 0, 0); \
  } while (0)
#define STG_B(h, kt, BUF) do { \
    const ushort_t* s_ = Bg + (size_t)(n0 + (h) * 128 + rth) * 512 + (kt) * 64 + swc; \
    __builtin_amdgcn_global_load_lds(AS1(s_), AS3(&Bs[BUF][h][tid * 8]), 16, 0, 0); \
    __builtin_amdgcn_global_load_lds(AS1(s_ + 64 * 512), AS3(&Bs[BUF][h][4096 + tid * 8]), 16, 0, 0); \
  } while (0)

#define BARR __builtin_amdgcn_s_barrier()
#define LGKM0 do { asm volatile("s_waitcnt lgkmcnt(0)" ::: "memory"); \
                   __builtin_amdgcn_sched_barrier(0); } while (0)
#define MF16(AF, BF, OFS) do { \
    __builtin_amdgcn_s_setprio(1); \
    _Pragma("unroll") for (int mf_ = 0; mf_ < 4; ++mf_) \
    _Pragma("unroll") for (int nf_ = 0; nf_ < 4; ++nf_) \
      acc[(OFS) + mf_][nf_] = __builtin_amdgcn_mfma_f32_16x16x32_bf16( \
          AF[mf_], BF[nf_], acc[(OFS) + mf_][nf_], 0, 0, 0); \
    __builtin_amdgcn_s_setprio(0); \
  } while (0)

#define TILE(T, CUR, DO_B1, DO_T2, VMN) do { \
    short8 a0[4], a1[4], a2[4], a3[4], b0[4], b1[4]; \
    _Pragma("unroll") for (int i = 0; i < 4; ++i) \
      a0[i] = *(const short8*)&As[CUR][wm][(i * 16 + fr) * 64 + s0]; \
    _Pragma("unroll") for (int i = 0; i < 4; ++i) \
      b0[i] = *(const short8*)&Bs[CUR][hB][(rB0 + i * 16 + fr) * 64 + s0]; \
    if (DO_B1) STG_B(1, (T) + 1, (CUR) ^ 1); \
    BARR; LGKM0; MF16(a0, b0, 0); BARR; \
    _Pragma("unroll") for (int i = 0; i < 4; ++i) \
      a1[i] = *(const short8*)&As[CUR][wm][((i + 4) * 16 + fr) * 64 + s0]; \
    _Pragma("unroll") for (int i = 0; i < 4; ++i) \
      b1[i] = *(const short8*)&Bs[CUR][hB][(rB0 + i * 16 + fr) * 64 + s1]; \
    BARR; LGKM0; MF16(a1, b0, 4); BARR; \
    _Pragma("unroll") for (int i = 0; i < 4; ++i) \
      a2[i] = *(const short8*)&As[CUR][wm][(i * 16 + fr) * 64 + s1]; \
    _Pragma("unroll") for (int i = 0; i < 4; ++i) \
      a3[i] = *(const short8*)&As[CUR][wm][((i + 4) * 16 + fr) * 64 + s1]; \
    if (DO_T2) STG_B(0, (T) + 2, (CUR)); \
    BARR; LGKM0; MF16(a2, b1, 0); BARR; \
    if (DO_T2) { STG_A(0, (T) + 2, (CUR)); STG_A(1, (T) + 2, (CUR)); } \
    if ((VMN) == 6) asm volatile("s_waitcnt vmcnt(6)" ::: "memory"); \
    else if ((VMN) == 0) asm volatile("s_waitcnt vmcnt(0)" ::: "memory"); \
    BARR; MF16(a3, b1, 4); BARR; \
  } while (0)

  asm volatile("s_waitcnt vmcnt(0)" ::: "memory");
  STG_A(0, 0, 0); STG_A(1, 0, 0); STG_B(0, 0, 0); STG_B(1, 0, 0);
  STG_B(0, 1, 1); STG_A(0, 1, 1); STG_A(1, 1, 1);
  asm volatile("s_waitcnt vmcnt(6)" ::: "memory");
  BARR;

  for (int t = 0; t < 6; t += 2) { TILE(t, 0, 1, 1, 6); TILE(t + 1, 1, 1, 1, 6); }
  TILE(6, 0, 1, 0, 0);
  TILE(7, 1, 0, 0, -1);

#undef TILE
#undef STG_A
#undef STG_B

  // ===== epilogue via LDS roundtrip: P rows (g,ph), bias, zero-pad =====
  us8 z = {0, 0, 0, 0, 0, 0, 0, 0};
#pragma unroll
  for (int p = 0; p < 2; ++p) {
    if (wm == p) {
#pragma unroll
      for (int m = 0; m < 8; ++m) {
#pragma unroll
        for (int n = 0; n < 4; ++n) {
          int col = wn * 64 + n * 16 + fr;
#pragma unroll
          for (int r = 0; r < 4; ++r) {
            int lrow = m * 16 + fk * 4 + r;
            SM[lrow * 264 + col] = f2b(acc[m][n][r] + bias[m0 + p * 128 + lrow]);
          }
        }
      }
    }
    BARR;
#pragma unroll
    for (int it = 0; it < 8; ++it) {
      int idx = it * 512 + tid;
      int row = idx >> 5, ch = idx & 31;
      int gcol = n0 + ch * 8;
      if (gcol < PLD) {
        us8 v = (gcol < NSP) ? *reinterpret_cast<const us8*>(&SM[row * 264 + ch * 8]) : z;
        *reinterpret_cast<us8*>(
            &P[(size_t)b * 512 * PLD + (size_t)(m0 + p * 128 + row) * PLD + gcol]) = v;
      }
    }
    BARR;
  }
#undef BARR
#undef LGKM0
#undef MF16
}

// ===================== gfinal: out = Z .NT xb + x + c0 ======================
__global__ __launch_bounds__(512, 2) void gfinal(
    const ushort_t* __restrict__ Zb,
    const ushort_t* __restrict__ xbase,
    float* __restrict__ out,
    const float* __restrict__ xres,
    const float* __restrict__ c0)
{
  const int nwg = gridDim.x * gridDim.y * gridDim.z;   // 416, %8==0
  int flat = blockIdx.x + gridDim.x * (blockIdx.y + gridDim.y * blockIdx.z);
  const int q = nwg >> 3;
  int swz = (flat & 7) * q + (flat >> 3);
  const int bx = swz % gridDim.x; int tmp = swz / gridDim.x;
  const int by = tmp % gridDim.y;
  const int b  = tmp / gridDim.y;

  const int m0 = bx * 256;
  const int n0 = by * 256;
  const ushort_t* Ag = Zb + (size_t)b * 262144;
  const ushort_t* Bg = xbase + (size_t)b * XNR * 512;

  const int tid = threadIdx.x;
  const int lane = tid & 63;
  const int wid = tid >> 6;
  const int wm = wid >> 2;
  const int wn = wid & 3;
  const int fr = lane & 15;
  const int fk = lane >> 4;
  const int hB = wn >> 1;
  const int rB0 = (wn & 1) * 64;
  const int s0 = ((fk) ^ (fr & 7)) * 8;
  const int s1 = ((4 | fk) ^ (fr & 7)) * 8;
  const int rth = tid >> 3;
  const int swc = ((tid & 7) ^ ((tid >> 3) & 7)) * 8;

  __shared__ __align__(16) ushort_t SM[65536];
  ushort_t (*As)[2][8192] = (ushort_t(*)[2][8192])(SM);
  ushort_t (*Bs)[2][8192] = (ushort_t(*)[2][8192])(SM + 32768);

  f32x4 acc[8][4];
#pragma unroll
  for (int i = 0; i < 8; ++i)
#pragma unroll
    for (int j = 0; j < 4; ++j) acc[i][j] = f32x4{0.f, 0.f, 0.f, 0.f};

#define STG_A(h, kt, BUF) do { \
    const ushort_t* s_ = Ag + (size_t)(m0 + (h) * 128 + rth) * 512 + (kt) * 64 + swc; \
    __builtin_amdgcn_global_load_lds(AS1(s_), AS3(&As[BUF][h][tid * 8]), 16, 0, 0); \
    __builtin_amdgcn_global_load_lds(AS1(s_ + 64 * 512), AS3(&As[BUF][h][4096 + tid * 8]), 16, 0, 0); \
  } while (0)
#define STG_B(h, kt, BUF) do { \
    const ushort_t* s_ = Bg + (size_t)(n0 + (h) * 128 + rth) * 512 + (kt) * 64 + swc; \
    __builtin_amdgcn_global_load_lds(AS1(s_), AS3(&Bs[BUF][h][tid * 8]), 16, 0, 0); \
    __builtin_amdgcn_global_load_lds(AS1(s_ + 64 * 512), AS3(&Bs[BUF][h][4096 + tid * 8]), 16, 0, 0); \
  } while (0)

#define BARR __builtin_amdgcn_s_barrier()
#define LGKM0 do { asm volatile("s_waitcnt lgkmcnt(0)" ::: "memory"); \
                   __builtin_amdgcn_sched_barrier(0); } while (0)
#define MF16(AF, BF, OFS) do { \
    __builtin_amdgcn_s_setprio(1); \
    _Pragma("unroll") for (int mf_ = 0; mf_ < 4; ++mf_) \
    _Pragma("unroll") for (int nf_ = 0; nf_ < 4; ++nf_) \
      acc[(OFS) + mf_][nf_] = __builtin_amdgcn_mfma_f32_16x16x32_bf16( \
          AF[mf_], BF[nf_], acc[(OFS) + mf_][nf_], 0, 0, 0); \
    __builtin_amdgcn_s_setprio(0); \
  } while (0)

#define TILE(T, CUR, DO_B1, DO_T2, VMN) do { \
    short8 a0[4], a1[4], a2[4], a3[4], b0[4], b1[4]; \
    _Pragma("unroll") for (int i = 0; i < 4; ++i) \
      a0[i] = *(const short8*)&As[CUR][wm][(i * 16 + fr) * 64 + s0]; \
    _Pragma("unroll") for (int i = 0; i < 4; ++i) \
      b0[i] = *(const short8*)&Bs[CUR][hB][(rB0 + i * 16 + fr) * 64 + s0]; \
    if (DO_B1) STG_B(1, (T) + 1, (CUR) ^ 1); \
    BARR; LGKM0; MF16(a0, b0, 0); BARR; \
    _Pragma("unroll") for (int i = 0; i < 4; ++i) \
      a1[i] = *(const short8*)&As[CUR][wm][((i + 4) * 16 + fr) * 64 + s0]; \
    _Pragma("unroll") for (int i = 0; i < 4; ++i) \
      b1[i] = *(const short8*)&Bs[CUR][hB][(rB0 + i * 16 + fr) * 64 + s1]; \
    BARR; LGKM0; MF16(a1, b0, 4); BARR; \
    _Pragma("unroll") for (int i = 0; i < 4; ++i) \
      a2[i] = *(const short8*)&As[CUR][wm][(i * 16 + fr) * 64 + s1]; \
    _Pragma("unroll") for (int i = 0; i < 4; ++i) \
      a3[i] = *(const short8*)&As[CUR][wm][((i + 4) * 16 + fr) * 64 + s1]; \
    if (DO_T2) STG_B(0, (T) + 2, (CUR)); \
    BARR; LGKM0; MF16(a2, b1, 0); BARR; \
    if (DO_T2) { STG_A(0, (T) + 2, (CUR)); STG_A(1, (T) + 2, (CUR)); } \
    if ((VMN) == 6) asm volatile("s_waitcnt vmcnt(6)" ::: "memory"); \
    else if ((VMN) == 0) asm volatile("s_waitcnt vmcnt(0)" ::: "memory"); \
    BARR; MF16(a3, b1, 4); BARR; \
  } while (0)

  asm volatile("s_waitcnt vmcnt(0)" ::: "memory");
  STG_A(0, 0, 0); STG_A(1, 0, 0); STG_B(0, 0, 0); STG_B(1, 0, 0);
  STG_B(0, 1, 1); STG_A(0, 1, 1); STG_A(1, 1, 1);
  asm volatile("s_waitcnt vmcnt(6)" ::: "memory");
  BARR;

  for (int t = 0; t < 6; t += 2) { TILE(t, 0, 1, 1, 6); TILE(t + 1, 1, 1, 1, 6); }
  TILE(6, 0, 1, 0, 0);
  TILE(7, 1, 0, 0, -1);

#undef TILE
#undef STG_A
#undef STG_B

  // ===== f32 epilogue via LDS roundtrip: out = acc + x + c0[row] =====
  float* SMf = (float*)SM;          // 128 x 256 f32 = 128 KiB exactly
  const float* c0v = c0 + (size_t)b * 512;
#pragma unroll
  for (int p = 0; p < 2; ++p) {
    if (wm == p) {
#pragma unroll
      for (int m = 0; m < 8; ++m)
#pragma unroll
        for (int n = 0; n < 4; ++n) {
          int col = wn * 64 + n * 16 + fr;
#pragma unroll
          for (int r = 0; r < 4; ++r)
            SMf[(m * 16 + fk * 4 + r) * 256 + col] = acc[m][n][r];
        }
    }
    BARR;
#pragma unroll
    for (int it = 0; it < 16; ++it) {
      int idx = it * 512 + tid;
      int row = idx >> 6, ch = idx & 63;
      int gcol = n0 + ch * 4;
      if (gcol < NSP) {
        int grow = m0 + p * 128 + row;
        size_t o = ((size_t)b * 512 + grow) * (size_t)NSP + gcol;
        f32x4 v = *reinterpret_cast<const f32x4*>(&SMf[row * 256 + ch * 4]);
        f32x4 xr = *reinterpret_cast<const f32x4*>(&xres[o]);
        float bi = c0v[grow];
        f32x4 ov = {v[0] + bi + xr[0], v[1] + bi + xr[1],
                    v[2] + bi + xr[2], v[3] + bi + xr[3]};
        *reinterpret_cast<f32x4*>(&out[o]) = ov;
      }
    }
    BARR;
  }
#undef BARR
#undef LGKM0
#undef MF16
}

// ==================== small GEMMs (128^2, BK=64, swizzled) ====================
// MODE 2: Mf2 = ph .NT g    (M=256, N=256, K=3200 split 5x640) f32
// MODE 6: U   = Ww .NT MT2  (M=512, N=256, K=256) bf16
// MODE 7: Z   = U  .NT TwT  (M=512, N=512, K=256) bf16
template<int MODE>
__global__ __launch_bounds__(256, 2) void gemm64(
    const ushort_t* __restrict__ Abase,
    const ushort_t* __restrict__ Bbase,
    void* __restrict__ Cbase)
{
  constexpr int TB = 256;
  constexpr int MR = 4;
  constexpr int WN = 2;
  constexpr int CH = TB / 8;

  const int nwg = gridDim.x * gridDim.y * gridDim.z;
  int flat = blockIdx.x + gridDim.x * (blockIdx.y + gridDim.y * blockIdx.z);
  const int q = nwg >> 3;
  int swz = (flat & 7) * q + (flat >> 3);
  const int bx = swz % gridDim.x; int tmp = swz / gridDim.x;
  const int by = tmp % gridDim.y;
  const int bz = tmp / gridDim.y;

  int b = bz, kc = 0, kbeg = 0, kend, lda, ldb;
  const ushort_t *A, *B;
  if constexpr (MODE == 2) {
    b = bz & 15; kc = bz >> 4;
    A = Abase + (size_t)b * 512 * PLD + (size_t)256 * PLD;  // ph
    B = Abase + (size_t)b * 512 * PLD;                      // g
    lda = PLD; ldb = PLD; kbeg = kc * 640; kend = kbeg + 640;
  } else if constexpr (MODE == 6) {
    A = Abase; lda = 256;
    B = Bbase + (size_t)b * 65536; ldb = 256;
    kend = 256;
  } else {
    A = Abase + (size_t)b * 131072; lda = 256;   // U_b
    B = Bbase; ldb = 256;                        // TwT
    kend = 256;
  }

  const int m0 = bx * 128;
  const int n0 = by * 128;
  const int tid = threadIdx.x;
  const int lane = tid & 63;
  const int wid = tid >> 6;
  const int wm = wid / WN, wn = wid % WN;
  const int fr = lane & 15;
  const int fk = lane >> 4;

  __shared__ __align__(16) ushort_t As[2][128 * 64];
  __shared__ __align__(16) ushort_t Bs[2][128 * 64];

  f32x4 acc[MR][4];
#pragma unroll
  for (int i = 0; i < MR; ++i)
#pragma unroll
    for (int j = 0; j < 4; ++j) acc[i][j] = f32x4{0.f, 0.f, 0.f, 0.f};

  const int srow = tid >> 3;
  const int lsl = (tid & 7) ^ (srow & 7);
  const ushort_t* pa = A + (size_t)(m0 + srow) * lda + kbeg + lsl * 8;
  const ushort_t* pb = B + (size_t)(n0 + srow) * ldb + kbeg + lsl * 8;

#define STAGE(bufi) do {                                                              \
    __builtin_amdgcn_global_load_lds(AS1(pa),                    AS3(&As[bufi][tid * 8]), 16, 0, 0); \
    __builtin_amdgcn_global_load_lds(AS1(pa + (size_t)CH * lda), AS3(&As[bufi][TB * 8 + tid * 8]), 16, 0, 0); \
    __builtin_amdgcn_global_load_lds(AS1(pa + (size_t)2 * CH * lda), AS3(&As[bufi][2 * TB * 8 + tid * 8]), 16, 0, 0); \
    __builtin_amdgcn_global_load_lds(AS1(pa + (size_t)3 * CH * lda), AS3(&As[bufi][3 * TB * 8 + tid * 8]), 16, 0, 0); \
    __builtin_amdgcn_global_load_lds(AS1(pb),                    AS3(&Bs[bufi][tid * 8]), 16, 0, 0); \
    __builtin_amdgcn_global_load_lds(AS1(pb + (size_t)CH * ldb), AS3(&Bs[bufi][TB * 8 + tid * 8]), 16, 0, 0); \
    __builtin_amdgcn_global_load_lds(AS1(pb + (size_t)2 * CH * ldb), AS3(&Bs[bufi][2 * TB * 8 + tid * 8]), 16, 0, 0); \
    __builtin_amdgcn_global_load_lds(AS1(pb + (size_t)3 * CH * ldb), AS3(&Bs[bufi][3 * TB * 8 + tid * 8]), 16, 0, 0); \
    pa += 64; pb += 64;                                                               \
  } while (0)

  const int sw = fr & 7;
  const int s0 = ((0 | fk) ^ sw) * 8;
  const int s1 = ((4 | fk) ^ sw) * 8;
  const int arow = (wm * MR * 16 + fr) * 64;
  const int brow = (wn * 64 + fr) * 64;

  asm volatile("s_waitcnt vmcnt(0)" ::: "memory");
  STAGE(0);

  const int nkt = (kend - kbeg) >> 6;
  for (int t = 0; t < nkt; ++t) {
    const int cur = t & 1;
    if (t + 1 < nkt) {
      STAGE(cur ^ 1);
      asm volatile("s_waitcnt vmcnt(8)" ::: "memory");
    } else {
      asm volatile("s_waitcnt vmcnt(0)" ::: "memory");
    }
    __builtin_amdgcn_s_barrier();
    __builtin_amdgcn_sched_barrier(0);

    short8 bf[4][2];
#pragma unroll
    for (int n = 0; n < 4; ++n) {
      bf[n][0] = *reinterpret_cast<const short8*>(&Bs[cur][brow + n * 1024 + s0]);
      bf[n][1] = *reinterpret_cast<const short8*>(&Bs[cur][brow + n * 1024 + s1]);
    }
    short8 af[4][2];
#pragma unroll
    for (int m = 0; m < 4; ++m) {
      af[m][0] = *reinterpret_cast<const short8*>(&As[cur][arow + m * 1024 + s0]);
      af[m][1] = *reinterpret_cast<const short8*>(&As[cur][arow + m * 1024 + s1]);
    }
    __builtin_amdgcn_s_setprio(1);
#pragma unroll
    for (int m = 0; m < 4; ++m)
#pragma unroll
      for (int n = 0; n < 4; ++n) {
        acc[m][n] = __builtin_amdgcn_mfma_f32_16x16x32_bf16(af[m][0], bf[n][0], acc[m][n], 0, 0, 0);
        acc[m][n] = __builtin_amdgcn_mfma_f32_16x16x32_bf16(af[m][1], bf[n][1], acc[m][n], 0, 0, 0);
      }
    __builtin_amdgcn_s_setprio(0);
    __builtin_amdgcn_s_barrier();
  }
#undef STAGE

  if constexpr (MODE == 2) {
    float* Mf = (float*)Cbase;
#pragma unroll
    for (int m = 0; m < MR; ++m)
#pragma unroll
      for (int n = 0; n < 4; ++n) {
        int gcol = n0 + wn * 64 + n * 16 + fr;
#pragma unroll
        for (int r = 0; r < 4; ++r) {
          int grow = m0 + wm * 64 + m * 16 + fk * 4 + r;
          Mf[((size_t)kc * 16 + b) * 65536 + grow * 256 + gcol] = acc[m][n][r];
        }
      }
  } else if constexpr (MODE == 6) {
    ushort_t* U = (ushort_t*)Cbase;
#pragma unroll
    for (int m = 0; m < MR; ++m)
#pragma unroll
      for (int n = 0; n < 4; ++n) {
        int gcol = n0 + wn * 64 + n * 16 + fr;
#pragma unroll
        for (int r = 0; r < 4; ++r) {
          int grow = m0 + wm * 64 + m * 16 + fk * 4 + r;
          U[(size_t)b * 131072 + grow * 256 + gcol] = f2b(acc[m][n][r]);
        }
      }
  } else {
    ushort_t* Z = (ushort_t*)Cbase;
#pragma unroll
    for (int m = 0; m < MR; ++m)
#pragma unroll
      for (int n = 0; n < 4; ++n) {
        int gcol = n0 + wn * 64 + n * 16 + fr;
#pragma unroll
        for (int r = 0; r < 4; ++r) {
          int grow = m0 + wm * 64 + m * 16 + fk * 4 + r;
          Z[(size_t)b * 262144 + (size_t)grow * 512 + gcol] = f2b(acc[m][n][r]);
        }
      }
  }
}

// x [b][512][3136] f32 -> xb [b][3200][512] bf16 (rows 3136..3199 zeroed)
__global__ __launch_bounds__(256) void transp_x(const float* __restrict__ x,
                                                ushort_t* __restrict__ xb)
{
  const int nt = blockIdx.x, ct = blockIdx.y, b = blockIdx.z;
  const int t = threadIdx.x;
  const int n0 = nt * 64, c0 = ct * 64;
  __shared__ float Ls[64 * 65];

  if (nt == 49) {
    us8 z = {0, 0, 0, 0, 0, 0, 0, 0};
#pragma unroll
    for (int it = 0; it < 2; ++it) {
      int idx = it * 256 + t; int nl = idx >> 3, cc = idx & 7;
      *reinterpret_cast<us8*>(&xb[((size_t)b * XNR + n0 + nl) * 512 + c0 + cc * 8]) = z;
    }
    return;
  }
  const float* xs = x + (size_t)b * 512 * NSP;
#pragma unroll
  for (int p = 0; p < 4; ++p) {
    int cl = p * 16 + (t >> 4);
    int nl = (t & 15) * 4;
    f32x4 v = *reinterpret_cast<const f32x4*>(&xs[(size_t)(c0 + cl) * NSP + n0 + nl]);
    Ls[cl * 65 + nl + 0] = v[0];
    Ls[cl * 65 + nl + 1] = v[1];
    Ls[cl * 65 + nl + 2] = v[2];
    Ls[cl * 65 + nl + 3] = v[3];
  }
  __syncthreads();
#pragma unroll
  for (int it = 0; it < 2; ++it) {
    int idx = it * 256 + t; int nl = idx >> 3, cc = idx & 7;
    us8 o;
#pragma unroll
    for (int j = 0; j < 8; ++j) o[j] = f2b(Ls[(cc * 8 + j) * 65 + nl]);
    *reinterpret_cast<us8*>(&xb[((size_t)b * XNR + n0 + nl) * 512 + c0 + cc * 8]) = o;
  }
}

// weights: W2 = [g_w; ph_w] bf16, TwT[ct][j] = th_w[j][ct], Wwb = W_w bf16,
// bias2 = [g_b; ph_b]
__global__ __launch_bounds__(256) void prep_weights(
    const float* __restrict__ g_w, const float* __restrict__ ph_w,
    const float* __restrict__ th_w, const float* __restrict__ W_w,
    const float* __restrict__ g_b, const float* __restrict__ ph_b,
    ushort_t* __restrict__ W2, ushort_t* __restrict__ TwT,
    ushort_t* __restrict__ Wwb, float* __restrict__ bias2)
{
  int i = blockIdx.x * 256 + threadIdx.x;
  if (i < 262144) {
    int row = i >> 9, col = i & 511;
    float v = (row < 256) ? g_w[row * 512 + col] : ph_w[(row - 256) * 512 + col];
    W2[i] = f2b(v);
  } else if (i < 393216) {
    int j = i - 262144; int ct = j >> 8; int k = j & 255;
    TwT[j] = f2b(th_w[(size_t)k * 512 + ct]);
  } else if (i < 524288) {
    Wwb[i - 393216] = f2b(W_w[i - 393216]);
  } else if (i < 524800) {
    int r = i - 524288;
    bias2[r] = (r < 256) ? g_b[r] : ph_b[r - 256];
  }
}

__global__ __launch_bounds__(256) void cvt_M(const float* __restrict__ Mf,
                                             ushort_t* __restrict__ MT)
{
  int i = blockIdx.x * 256 + threadIdx.x;   // 16*256*256
  const int SL = 1048576;
  float s = 0.f;
#pragma unroll
  for (int k = 0; k < 5; ++k) s += Mf[(size_t)k * SL + i];
  MT[i] = f2b(s * (1.0f / 3136.0f));
}

// c0[b][c] = sum_j U[b][c][j]*th_b[j] + W_b[c]
__global__ __launch_bounds__(256) void u3k(const ushort_t* __restrict__ U,
                                           const float* __restrict__ th_b,
                                           const float* __restrict__ W_b,
                                           float* __restrict__ c0)
{
  int i = blockIdx.x * 256 + threadIdx.x;   // 16*512 = 8192
  int c = i & 511;
  const ushort_t* Ur = U + (size_t)i * 256;
  float a = 0.f;
#pragma unroll 4
  for (int j = 0; j < 256; ++j) a += b2f(Ur[j]) * th_b[j];
  c0[i] = a + W_b[c];
}

extern "C" void kernel_launch(void* const* d_in, const int* in_sizes, int n_in,
                              void* d_out, int out_size, void* d_ws, size_t ws_size,
                              hipStream_t stream) {
  const float* x    = (const float*)d_in[0];
  const float* g_w  = (const float*)d_in[1];
  const float* g_b  = (const float*)d_in[2];
  const float* th_w = (const float*)d_in[3];
  const float* th_b = (const float*)d_in[4];
  const float* ph_w = (const float*)d_in[5];
  const float* ph_b = (const float*)d_in[6];
  const float* W_w  = (const float*)d_in[7];
  const float* W_b  = (const float*)d_in[8];

  char* ws = (char*)d_ws;
  ushort_t* xb   = (ushort_t*)(ws + 0);            // 52,428,800
  ushort_t* P    = (ushort_t*)(ws + 52428800);     // 52,428,800 (dead after G2)
  ushort_t* U    = (ushort_t*)(ws + 52428800);     // 4,194,304 (aliases P)
  ushort_t* Z    = (ushort_t*)(ws + 56623104);     // 8,388,608 (aliases P)
  float*    Mf2  = (float*)(ws + 104857600);       // 20,971,520
  ushort_t* MT2  = (ushort_t*)(ws + 125829120);    // 2,097,152
  ushort_t* W2   = (ushort_t*)(ws + 127926272);    // 524,288
  ushort_t* TwT  = (ushort_t*)(ws + 128450560);    // 262,144
  ushort_t* Wwb  = (ushort_t*)(ws + 128712704);    // 262,144
  float*    bias2 = (float*)(ws + 128974848);      // 2,048
  float*    c0   = (float*)(ws + 128976896);       // 32,768   total ~129 MB

  prep_weights<<<2051, 256, 0, stream>>>(g_w, ph_w, th_w, W_w, g_b, ph_b,
                                         W2, TwT, Wwb, bias2);
  transp_x<<<dim3(50, 8, 16), 256, 0, stream>>>(x, xb);

  // G1: P(g,ph) = W2 .NT xb (+bias2)   M=512, N=3328-tiled, K=512
  g1_8phase<<<dim3(2, 13, 16), 512, 0, stream>>>(W2, xb, P, bias2);
  // G2: Mf2 partials = ph .NT g   split-K 5x640
  gemm64<2><<<dim3(2, 2, 80), 256, 0, stream>>>(P, nullptr, Mf2);
  cvt_M<<<4096, 256, 0, stream>>>(Mf2, MT2);
  // GU: U = Wwb .NT MT2            M=512, N=256, K=256
  gemm64<6><<<dim3(4, 2, 16), 256, 0, stream>>>(Wwb, MT2, U);
  // Zg: Z = U .NT TwT              M=512, N=512, K=256
  gemm64<7><<<dim3(4, 4, 16), 256, 0, stream>>>(U, TwT, Z);
  // c0 = U th_b + W_b
  u3k<<<32, 256, 0, stream>>>(U, th_b, W_b, c0);
  // out = Z .NT xb + x + c0
  gfinal<<<dim3(2, 13, 16), 512, 0, stream>>>(Z, xb, (float*)d_out, x, c0);
}

// Round 10
// 177.442 us; speedup vs baseline: 1.6049x; 1.0526x over previous
//
#include <hip/hip_runtime.h>
#include <stdint.h>

// ---------------------------------------------------------------------------
// NonLocalBlock2D  B=16, C=512, I=256, N=3136.   (R7 pipeline, G4 -> 8-phase)
//   xb  [b][3200][512] = x^T bf16
//   G1 (256^2, 8-phase): rows<512 -> P[b][512][3200] (g,ph)
//                        rows>=512 -> thT[b][3136][256] (transposed store)
//   G2 (128^2): Mf2 partials = ph .NT g, split-K 5x640
//   cvt: MT2 = (1/N) sum partials
//   GU (128^2): U = Ww .NT MT2
//   G4 (256^2, 8-phase, nkt=4): out = U .NT thT + x + W_b (f32 LDS epilogue)
// ---------------------------------------------------------------------------

typedef unsigned short ushort_t;
typedef __attribute__((ext_vector_type(8))) short short8;
typedef __attribute__((ext_vector_type(4))) float f32x4;
typedef __attribute__((ext_vector_type(4))) unsigned short us4;
typedef __attribute__((ext_vector_type(8))) unsigned short us8;

#define NSP  3136
#define XNR  3200
#define PLD  3200

#define AS1(p) ((const __attribute__((address_space(1))) void*)(p))
#define AS3(p) ((__attribute__((address_space(3))) void*)(p))

__device__ inline ushort_t f2b(float f) {
  union { float f; uint32_t u; } c; c.f = f;
  uint32_t u = c.u;
  uint32_t r = (u + 0x7fffu + ((u >> 16) & 1u)) >> 16;
  return (ushort_t)r;
}

// ============================ G1: 8-phase 256^2 ============================
__global__ __launch_bounds__(512, 2) void g1_8phase(
    const ushort_t* __restrict__ W3,
    const ushort_t* __restrict__ xbase,
    ushort_t* __restrict__ P,
    ushort_t* __restrict__ thT,
    const float* __restrict__ bias)
{
  const int nwg = gridDim.x * gridDim.y * gridDim.z;   // 624, %8==0
  int flat = blockIdx.x + gridDim.x * (blockIdx.y + gridDim.y * blockIdx.z);
  const int q = nwg >> 3;
  int swz = (flat & 7) * q + (flat >> 3);
  const int bx = swz % gridDim.x; int tmp = swz / gridDim.x;
  const int by = tmp % gridDim.y;
  const int b  = tmp / gridDim.y;

  const int m0 = bx * 256;
  const int n0 = by * 256;
  const ushort_t* Ag = W3;
  const ushort_t* Bg = xbase + (size_t)b * XNR * 512;

  const int tid = threadIdx.x;
  const int lane = tid & 63;
  const int wid = tid >> 6;
  const int wm = wid >> 2;            // 0..1  (m-half)
  const int wn = wid & 3;             // 0..3
  const int fr = lane & 15;
  const int fk = lane >> 4;           // 0..3
  const int hB = wn >> 1;             // B half
  const int rB0 = (wn & 1) * 64;
  const int s0 = ((fk) ^ (fr & 7)) * 8;
  const int s1 = ((4 | fk) ^ (fr & 7)) * 8;
  const int rth = tid >> 3;
  const int swc = ((tid & 7) ^ ((tid >> 3) & 7)) * 8;

  __shared__ __align__(16) ushort_t SM[65536];          // 128 KiB
  ushort_t (*As)[2][8192] = (ushort_t(*)[2][8192])(SM);
  ushort_t (*Bs)[2][8192] = (ushort_t(*)[2][8192])(SM + 32768);

  f32x4 acc[8][4];
#pragma unroll
  for (int i = 0; i < 8; ++i)
#pragma unroll
    for (int j = 0; j < 4; ++j) acc[i][j] = f32x4{0.f, 0.f, 0.f, 0.f};

#define STG_A(h, kt, BUF) do { \
    const ushort_t* s_ = Ag + (size_t)(m0 + (h) * 128 + rth) * 512 + (kt) * 64 + swc; \
    __builtin_amdgcn_global_load_lds(AS1(s_), AS3(&As[BUF][h][tid * 8]), 16, 0, 0); \
    __builtin_amdgcn_global_load_lds(AS1(s_ + 64 * 512), AS3(&As[BUF][h][4096 + tid * 8]), 16, 0, 0); \
  } while (0)
#define STG_B(h, kt, BUF) do { \
    const ushort_t* s_ = Bg + (size_t)(n0 + (h) * 128 + rth) * 512 + (kt) * 64 + swc; \
    __builtin_amdgcn_global_load_lds(AS1(s_), AS3(&Bs[BUF][h][tid * 8]), 16, 0, 0); \
    __builtin_amdgcn_global_load_lds(AS1(s_ + 64 * 512), AS3(&Bs[BUF][h][4096 + tid * 8]), 16, 0, 0); \
  } while (0)

#define BARR __builtin_amdgcn_s_barrier()
#define LGKM0 do { asm volatile("s_waitcnt lgkmcnt(0)" ::: "memory"); \
                   __builtin_amdgcn_sched_barrier(0); } while (0)
#define MF16(AF, BF, OFS) do { \
    __builtin_amdgcn_s_setprio(1); \
    _Pragma("unroll") for (int mf_ = 0; mf_ < 4; ++mf_) \
    _Pragma("unroll") for (int nf_ = 0; nf_ < 4; ++nf_) \
      acc[(OFS) + mf_][nf_] = __builtin_amdgcn_mfma_f32_16x16x32_bf16( \
          AF[mf_], BF[nf_], acc[(OFS) + mf_][nf_], 0, 0, 0); \
    __builtin_amdgcn_s_setprio(0); \
  } while (0)

#define TILE(T, CUR, DO_B1, DO_T2, VMN) do { \
    short8 a0[4], a1[4], a2[4], a3[4], b0[4], b1[4]; \
    _Pragma("unroll") for (int i = 0; i < 4; ++i) \
      a0[i] = *(const short8*)&As[CUR][wm][(i * 16 + fr) * 64 + s0]; \
    _Pragma("unroll") for (int i = 0; i < 4; ++i) \
      b0[i] = *(const short8*)&Bs[CUR][hB][(rB0 + i * 16 + fr) * 64 + s0]; \
    if (DO_B1) STG_B(1, (T) + 1, (CUR) ^ 1); \
    BARR; LGKM0; MF16(a0, b0, 0); BARR; \
    _Pragma("unroll") for (int i = 0; i < 4; ++i) \
      a1[i] = *(const short8*)&As[CUR][wm][((i + 4) * 16 + fr) * 64 + s0]; \
    _Pragma("unroll") for (int i = 0; i < 4; ++i) \
      b1[i] = *(const short8*)&Bs[CUR][hB][(rB0 + i * 16 + fr) * 64 + s1]; \
    BARR; LGKM0; MF16(a1, b0, 4); BARR; \
    _Pragma("unroll") for (int i = 0; i < 4; ++i) \
      a2[i] = *(const short8*)&As[CUR][wm][(i * 16 + fr) * 64 + s1]; \
    _Pragma("unroll") for (int i = 0; i < 4; ++i) \
      a3[i] = *(const short8*)&As[CUR][wm][((i + 4) * 16 + fr) * 64 + s1]; \
    if (DO_T2) STG_B(0, (T) + 2, (CUR)); \
    BARR; LGKM0; MF16(a2, b1, 0); BARR; \
    if (DO_T2) { STG_A(0, (T) + 2, (CUR)); STG_A(1, (T) + 2, (CUR)); } \
    if ((VMN) == 6) asm volatile("s_waitcnt vmcnt(6)" ::: "memory"); \
    else if ((VMN) == 0) asm volatile("s_waitcnt vmcnt(0)" ::: "memory"); \
    BARR; MF16(a3, b1, 4); BARR; \
  } while (0)

  asm volatile("s_waitcnt vmcnt(0)" ::: "memory");
  STG_A(0, 0, 0); STG_A(1, 0, 0); STG_B(0, 0, 0); STG_B(1, 0, 0);
  STG_B(0, 1, 1); STG_A(0, 1, 1); STG_A(1, 1, 1);
  asm volatile("s_waitcnt vmcnt(6)" ::: "memory");
  BARR;

  for (int t = 0; t < 6; t += 2) { TILE(t, 0, 1, 1, 6); TILE(t + 1, 1, 1, 1, 6); }
  TILE(6, 0, 1, 0, 0);
  TILE(7, 1, 0, 0, -1);

#undef TILE
#undef STG_A
#undef STG_B

  // ======== epilogue via LDS roundtrip ========
  if (m0 == 512) {
    // thT: LDS [local col 0..127][264] ; 2 passes over col halves
#pragma unroll
    for (int p = 0; p < 2; ++p) {
      if ((wn >> 1) == p) {
        const int lcb = (wn & 1) * 64;
#pragma unroll
        for (int m = 0; m < 8; ++m) {
          int jr = wm * 128 + m * 16 + fk * 4;
#pragma unroll
          for (int n = 0; n < 4; ++n) {
            int lc = lcb + n * 16 + fr;
            us4 o;
#pragma unroll
            for (int r = 0; r < 4; ++r) o[r] = f2b(acc[m][n][r] + bias[512 + jr + r]);
            *reinterpret_cast<us4*>(&SM[lc * 264 + jr]) = o;
          }
        }
      }
      BARR;
#pragma unroll
      for (int it = 0; it < 8; ++it) {
        int idx = it * 512 + tid;
        int lc = idx >> 5, ch = idx & 31;
        int col = n0 + p * 128 + lc;
        if (col < NSP)
          *reinterpret_cast<us8*>(&thT[((size_t)b * NSP + col) * 256 + ch * 8]) =
              *reinterpret_cast<const us8*>(&SM[lc * 264 + ch * 8]);
      }
      BARR;
    }
  } else {
    // P (g/ph): LDS [local row 0..127][264] ; 2 passes over row halves
    us8 z = {0, 0, 0, 0, 0, 0, 0, 0};
#pragma unroll
    for (int p = 0; p < 2; ++p) {
      if (wm == p) {
#pragma unroll
        for (int m = 0; m < 8; ++m) {
#pragma unroll
          for (int n = 0; n < 4; ++n) {
            int col = wn * 64 + n * 16 + fr;
#pragma unroll
            for (int r = 0; r < 4; ++r) {
              int lrow = m * 16 + fk * 4 + r;
              SM[lrow * 264 + col] = f2b(acc[m][n][r] + bias[m0 + p * 128 + lrow]);
            }
          }
        }
      }
      BARR;
#pragma unroll
      for (int it = 0; it < 8; ++it) {
        int idx = it * 512 + tid;
        int row = idx >> 5, ch = idx & 31;
        int gcol = n0 + ch * 8;
        if (gcol < PLD) {
          us8 v = (gcol < NSP) ? *reinterpret_cast<const us8*>(&SM[row * 264 + ch * 8]) : z;
          *reinterpret_cast<us8*>(
              &P[(size_t)b * 512 * PLD + (size_t)(m0 + p * 128 + row) * PLD + gcol]) = v;
        }
      }
      BARR;
    }
  }
#undef BARR
#undef LGKM0
#undef MF16
}

// ============== G4: 8-phase 256^2, K=256 (nkt=4): out = U .NT thT + x + W_b ==============
__global__ __launch_bounds__(512, 2) void g4_8phase(
    const ushort_t* __restrict__ Ub,
    const ushort_t* __restrict__ thT,
    float* __restrict__ out,
    const float* __restrict__ xres,
    const float* __restrict__ Wb)
{
  const int nwg = gridDim.x * gridDim.y * gridDim.z;   // 416, %8==0
  int flat = blockIdx.x + gridDim.x * (blockIdx.y + gridDim.y * blockIdx.z);
  const int q = nwg >> 3;
  int swz = (flat & 7) * q + (flat >> 3);
  const int bx = swz % gridDim.x; int tmp = swz / gridDim.x;
  const int by = tmp % gridDim.y;
  const int b  = tmp / gridDim.y;

  const int m0 = bx * 256;
  const int n0 = by * 256;
  const ushort_t* Ag = Ub + (size_t)b * 131072;        // [512][256]
  const ushort_t* Bg = thT + (size_t)b * NSP * 256;    // [3136][256] (tail reads spill into P region; discarded)

  const int tid = threadIdx.x;
  const int lane = tid & 63;
  const int wid = tid >> 6;
  const int wm = wid >> 2;
  const int wn = wid & 3;
  const int fr = lane & 15;
  const int fk = lane >> 4;
  const int hB = wn >> 1;
  const int rB0 = (wn & 1) * 64;
  const int s0 = ((fk) ^ (fr & 7)) * 8;
  const int s1 = ((4 | fk) ^ (fr & 7)) * 8;
  const int rth = tid >> 3;
  const int swc = ((tid & 7) ^ ((tid >> 3) & 7)) * 8;

  __shared__ __align__(16) ushort_t SM[65536];
  ushort_t (*As)[2][8192] = (ushort_t(*)[2][8192])(SM);
  ushort_t (*Bs)[2][8192] = (ushort_t(*)[2][8192])(SM + 32768);

  f32x4 acc[8][4];
#pragma unroll
  for (int i = 0; i < 8; ++i)
#pragma unroll
    for (int j = 0; j < 4; ++j) acc[i][j] = f32x4{0.f, 0.f, 0.f, 0.f};

#define STG_A(h, kt, BUF) do { \
    const ushort_t* s_ = Ag + (size_t)(m0 + (h) * 128 + rth) * 256 + (kt) * 64 + swc; \
    __builtin_amdgcn_global_load_lds(AS1(s_), AS3(&As[BUF][h][tid * 8]), 16, 0, 0); \
    __builtin_amdgcn_global_load_lds(AS1(s_ + 64 * 256), AS3(&As[BUF][h][4096 + tid * 8]), 16, 0, 0); \
  } while (0)
#define STG_B(h, kt, BUF) do { \
    const ushort_t* s_ = Bg + (size_t)(n0 + (h) * 128 + rth) * 256 + (kt) * 64 + swc; \
    __builtin_amdgcn_global_load_lds(AS1(s_), AS3(&Bs[BUF][h][tid * 8]), 16, 0, 0); \
    __builtin_amdgcn_global_load_lds(AS1(s_ + 64 * 256), AS3(&Bs[BUF][h][4096 + tid * 8]), 16, 0, 0); \
  } while (0)

#define BARR __builtin_amdgcn_s_barrier()
#define LGKM0 do { asm volatile("s_waitcnt lgkmcnt(0)" ::: "memory"); \
                   __builtin_amdgcn_sched_barrier(0); } while (0)
#define MF16(AF, BF, OFS) do { \
    __builtin_amdgcn_s_setprio(1); \
    _Pragma("unroll") for (int mf_ = 0; mf_ < 4; ++mf_) \
    _Pragma("unroll") for (int nf_ = 0; nf_ < 4; ++nf_) \
      acc[(OFS) + mf_][nf_] = __builtin_amdgcn_mfma_f32_16x16x32_bf16( \
          AF[mf_], BF[nf_], acc[(OFS) + mf_][nf_], 0, 0, 0); \
    __builtin_amdgcn_s_setprio(0); \
  } while (0)

#define TILE(T, CUR, DO_B1, DO_T2, VMN) do { \
    short8 a0[4], a1[4], a2[4], a3[4], b0[4], b1[4]; \
    _Pragma("unroll") for (int i = 0; i < 4; ++i) \
      a0[i] = *(const short8*)&As[CUR][wm][(i * 16 + fr) * 64 + s0]; \
    _Pragma("unroll") for (int i = 0; i < 4; ++i) \
      b0[i] = *(const short8*)&Bs[CUR][hB][(rB0 + i * 16 + fr) * 64 + s0]; \
    if (DO_B1) STG_B(1, (T) + 1, (CUR) ^ 1); \
    BARR; LGKM0; MF16(a0, b0, 0); BARR; \
    _Pragma("unroll") for (int i = 0; i < 4; ++i) \
      a1[i] = *(const short8*)&As[CUR][wm][((i + 4) * 16 + fr) * 64 + s0]; \
    _Pragma("unroll") for (int i = 0; i < 4; ++i) \
      b1[i] = *(const short8*)&Bs[CUR][hB][(rB0 + i * 16 + fr) * 64 + s1]; \
    BARR; LGKM0; MF16(a1, b0, 4); BARR; \
    _Pragma("unroll") for (int i = 0; i < 4; ++i) \
      a2[i] = *(const short8*)&As[CUR][wm][(i * 16 + fr) * 64 + s1]; \
    _Pragma("unroll") for (int i = 0; i < 4; ++i) \
      a3[i] = *(const short8*)&As[CUR][wm][((i + 4) * 16 + fr) * 64 + s1]; \
    if (DO_T2) STG_B(0, (T) + 2, (CUR)); \
    BARR; LGKM0; MF16(a2, b1, 0); BARR; \
    if (DO_T2) { STG_A(0, (T) + 2, (CUR)); STG_A(1, (T) + 2, (CUR)); } \
    if ((VMN) == 6) asm volatile("s_waitcnt vmcnt(6)" ::: "memory"); \
    else if ((VMN) == 0) asm volatile("s_waitcnt vmcnt(0)" ::: "memory"); \
    BARR; MF16(a3, b1, 4); BARR; \
  } while (0)

  asm volatile("s_waitcnt vmcnt(0)" ::: "memory");
  STG_A(0, 0, 0); STG_A(1, 0, 0); STG_B(0, 0, 0); STG_B(1, 0, 0);
  STG_B(0, 1, 1); STG_A(0, 1, 1); STG_A(1, 1, 1);
  asm volatile("s_waitcnt vmcnt(6)" ::: "memory");
  BARR;

  // nkt = 4: same counted-vmcnt pattern, truncated
  TILE(0, 0, 1, 1, 6);
  TILE(1, 1, 1, 1, 6);
  TILE(2, 0, 1, 0, 0);
  TILE(3, 1, 0, 0, -1);

#undef TILE
#undef STG_A
#undef STG_B

  // ===== f32 epilogue via LDS roundtrip: out = acc + x + W_b[row] =====
  float* SMf = (float*)SM;          // 128 x 256 f32 = 128 KiB exactly
#pragma unroll
  for (int p = 0; p < 2; ++p) {
    if (wm == p) {
#pragma unroll
      for (int m = 0; m < 8; ++m)
#pragma unroll
        for (int n = 0; n < 4; ++n) {
          int col = wn * 64 + n * 16 + fr;
#pragma unroll
          for (int r = 0; r < 4; ++r)
            SMf[(m * 16 + fk * 4 + r) * 256 + col] = acc[m][n][r];
        }
    }
    BARR;
#pragma unroll
    for (int it = 0; it < 16; ++it) {
      int idx = it * 512 + tid;
      int row = idx >> 6, ch = idx & 63;
      int gcol = n0 + ch * 4;
      if (gcol < NSP) {
        int grow = m0 + p * 128 + row;
        size_t o = ((size_t)b * 512 + grow) * (size_t)NSP + gcol;
        f32x4 v = *reinterpret_cast<const f32x4*>(&SMf[row * 256 + ch * 4]);
        f32x4 xr = *reinterpret_cast<const f32x4*>(&xres[o]);
        float bi = Wb[grow];
        f32x4 ov = {v[0] + bi + xr[0], v[1] + bi + xr[1],
                    v[2] + bi + xr[2], v[3] + bi + xr[3]};
        *reinterpret_cast<f32x4*>(&out[o]) = ov;
      }
    }
    BARR;
  }
#undef BARR
#undef LGKM0
#undef MF16
}

// ==================== small GEMMs (128^2, BK=64, swizzled) ====================
// MODE 2: Mf2 = ph .NT g    (M=256, N=256, K=3200 split 5x640) f32
// MODE 6: U   = Ww .NT MT2  (M=512, N=256, K=256) bf16
template<int MODE>
__global__ __launch_bounds__(256, 2) void gemm64(
    const ushort_t* __restrict__ Abase,
    const ushort_t* __restrict__ Bbase,
    void* __restrict__ Cbase)
{
  constexpr int TB = 256;
  constexpr int MR = 4;
  constexpr int WN = 2;
  constexpr int CH = TB / 8;

  const int nwg = gridDim.x * gridDim.y * gridDim.z;
  int flat = blockIdx.x + gridDim.x * (blockIdx.y + gridDim.y * blockIdx.z);
  const int q = nwg >> 3;
  int swz = (flat & 7) * q + (flat >> 3);
  const int bx = swz % gridDim.x; int tmp = swz / gridDim.x;
  const int by = tmp % gridDim.y;
  const int bz = tmp / gridDim.y;

  int b = bz, kc = 0, kbeg = 0, kend, lda, ldb;
  const ushort_t *A, *B;
  if constexpr (MODE == 2) {
    b = bz & 15; kc = bz >> 4;
    A = Abase + (size_t)b * 512 * PLD + (size_t)256 * PLD;  // ph
    B = Abase + (size_t)b * 512 * PLD;                      // g
    lda = PLD; ldb = PLD; kbeg = kc * 640; kend = kbeg + 640;
  } else {
    A = Abase; lda = 256;
    B = Bbase + (size_t)b * 65536; ldb = 256;
    kend = 256;
  }

  const int m0 = bx * 128;
  const int n0 = by * 128;
  const int tid = threadIdx.x;
  const int lane = tid & 63;
  const int wid = tid >> 6;
  const int wm = wid / WN, wn = wid % WN;
  const int fr = lane & 15;
  const int fk = lane >> 4;

  __shared__ __align__(16) ushort_t As[2][128 * 64];
  __shared__ __align__(16) ushort_t Bs[2][128 * 64];

  f32x4 acc[MR][4];
#pragma unroll
  for (int i = 0; i < MR; ++i)
#pragma unroll
    for (int j = 0; j < 4; ++j) acc[i][j] = f32x4{0.f, 0.f, 0.f, 0.f};

  const int srow = tid >> 3;
  const int lsl = (tid & 7) ^ (srow & 7);
  const ushort_t* pa = A + (size_t)(m0 + srow) * lda + kbeg + lsl * 8;
  const ushort_t* pb = B + (size_t)(n0 + srow) * ldb + kbeg + lsl * 8;

#define STAGE(bufi) do {                                                              \
    __builtin_amdgcn_global_load_lds(AS1(pa),                    AS3(&As[bufi][tid * 8]), 16, 0, 0); \
    __builtin_amdgcn_global_load_lds(AS1(pa + (size_t)CH * lda), AS3(&As[bufi][TB * 8 + tid * 8]), 16, 0, 0); \
    __builtin_amdgcn_global_load_lds(AS1(pa + (size_t)2 * CH * lda), AS3(&As[bufi][2 * TB * 8 + tid * 8]), 16, 0, 0); \
    __builtin_amdgcn_global_load_lds(AS1(pa + (size_t)3 * CH * lda), AS3(&As[bufi][3 * TB * 8 + tid * 8]), 16, 0, 0); \
    __builtin_amdgcn_global_load_lds(AS1(pb),                    AS3(&Bs[bufi][tid * 8]), 16, 0, 0); \
    __builtin_amdgcn_global_load_lds(AS1(pb + (size_t)CH * ldb), AS3(&Bs[bufi][TB * 8 + tid * 8]), 16, 0, 0); \
    __builtin_amdgcn_global_load_lds(AS1(pb + (size_t)2 * CH * ldb), AS3(&Bs[bufi][2 * TB * 8 + tid * 8]), 16, 0, 0); \
    __builtin_amdgcn_global_load_lds(AS1(pb + (size_t)3 * CH * ldb), AS3(&Bs[bufi][3 * TB * 8 + tid * 8]), 16, 0, 0); \
    pa += 64; pb += 64;                                                               \
  } while (0)

  const int sw = fr & 7;
  const int s0 = ((0 | fk) ^ sw) * 8;
  const int s1 = ((4 | fk) ^ sw) * 8;
  const int arow = (wm * MR * 16 + fr) * 64;
  const int brow = (wn * 64 + fr) * 64;

  asm volatile("s_waitcnt vmcnt(0)" ::: "memory");
  STAGE(0);

  const int nkt = (kend - kbeg) >> 6;
  for (int t = 0; t < nkt; ++t) {
    const int cur = t & 1;
    if (t + 1 < nkt) {
      STAGE(cur ^ 1);
      asm volatile("s_waitcnt vmcnt(8)" ::: "memory");
    } else {
      asm volatile("s_waitcnt vmcnt(0)" ::: "memory");
    }
    __builtin_amdgcn_s_barrier();
    __builtin_amdgcn_sched_barrier(0);

    short8 bf[4][2];
#pragma unroll
    for (int n = 0; n < 4; ++n) {
      bf[n][0] = *reinterpret_cast<const short8*>(&Bs[cur][brow + n * 1024 + s0]);
      bf[n][1] = *reinterpret_cast<const short8*>(&Bs[cur][brow + n * 1024 + s1]);
    }
    short8 af[4][2];
#pragma unroll
    for (int m = 0; m < 4; ++m) {
      af[m][0] = *reinterpret_cast<const short8*>(&As[cur][arow + m * 1024 + s0]);
      af[m][1] = *reinterpret_cast<const short8*>(&As[cur][arow + m * 1024 + s1]);
    }
    __builtin_amdgcn_s_setprio(1);
#pragma unroll
    for (int m = 0; m < 4; ++m)
#pragma unroll
      for (int n = 0; n < 4; ++n) {
        acc[m][n] = __builtin_amdgcn_mfma_f32_16x16x32_bf16(af[m][0], bf[n][0], acc[m][n], 0, 0, 0);
        acc[m][n] = __builtin_amdgcn_mfma_f32_16x16x32_bf16(af[m][1], bf[n][1], acc[m][n], 0, 0, 0);
      }
    __builtin_amdgcn_s_setprio(0);
    __builtin_amdgcn_s_barrier();
  }
#undef STAGE

  if constexpr (MODE == 2) {
    float* Mf = (float*)Cbase;
#pragma unroll
    for (int m = 0; m < MR; ++m)
#pragma unroll
      for (int n = 0; n < 4; ++n) {
        int gcol = n0 + wn * 64 + n * 16 + fr;
#pragma unroll
        for (int r = 0; r < 4; ++r) {
          int grow = m0 + wm * 64 + m * 16 + fk * 4 + r;
          Mf[((size_t)kc * 16 + b) * 65536 + grow * 256 + gcol] = acc[m][n][r];
        }
      }
  } else {
    ushort_t* U = (ushort_t*)Cbase;
#pragma unroll
    for (int m = 0; m < MR; ++m)
#pragma unroll
      for (int n = 0; n < 4; ++n) {
        int gcol = n0 + wn * 64 + n * 16 + fr;
#pragma unroll
        for (int r = 0; r < 4; ++r) {
          int grow = m0 + wm * 64 + m * 16 + fk * 4 + r;
          U[(size_t)b * 131072 + grow * 256 + gcol] = f2b(acc[m][n][r]);
        }
      }
  }
}

// x [b][512][3136] f32 -> xb [b][3200][512] bf16
__global__ __launch_bounds__(256) void transp_x(const float* __restrict__ x,
                                                ushort_t* __restrict__ xb)
{
  const int nt = blockIdx.x, ct = blockIdx.y, b = blockIdx.z;
  const int t = threadIdx.x;
  const int n0 = nt * 64, c0 = ct * 64;
  __shared__ float Ls[64 * 65];

  const float* xs = x + (size_t)b * 512 * NSP;
#pragma unroll
  for (int p = 0; p < 4; ++p) {
    int cl = p * 16 + (t >> 4);
    int nl = (t & 15) * 4;
    f32x4 v = *reinterpret_cast<const f32x4*>(&xs[(size_t)(c0 + cl) * NSP + n0 + nl]);
    Ls[cl * 65 + nl + 0] = v[0];
    Ls[cl * 65 + nl + 1] = v[1];
    Ls[cl * 65 + nl + 2] = v[2];
    Ls[cl * 65 + nl + 3] = v[3];
  }
  __syncthreads();
#pragma unroll
  for (int it = 0; it < 2; ++it) {
    int idx = it * 256 + t; int nl = idx >> 3, cc = idx & 7;
    us8 o;
#pragma unroll
    for (int j = 0; j < 8; ++j) o[j] = f2b(Ls[(cc * 8 + j) * 65 + nl]);
    *reinterpret_cast<us8*>(&xb[((size_t)b * XNR + n0 + nl) * 512 + c0 + cc * 8]) = o;
  }
}

__global__ __launch_bounds__(256) void prep_weights(
    const float* __restrict__ g_w, const float* __restrict__ ph_w,
    const float* __restrict__ th_w, const float* __restrict__ W_w,
    const float* __restrict__ g_b, const float* __restrict__ ph_b,
    const float* __restrict__ th_b,
    ushort_t* __restrict__ W3, ushort_t* __restrict__ Wwb,
    float* __restrict__ bias3)
{
  int i = blockIdx.x * 256 + threadIdx.x;
  if (i < 393216) {
    int row = i >> 9, col = i & 511;
    float v = (row < 256) ? g_w[row * 512 + col]
            : (row < 512) ? ph_w[(row - 256) * 512 + col]
                          : th_w[(row - 512) * 512 + col];
    W3[i] = f2b(v);
  } else if (i < 524288) {
    Wwb[i - 393216] = f2b(W_w[i - 393216]);
  } else if (i < 525056) {
    int r = i - 524288;
    bias3[r] = (r < 256) ? g_b[r] : (r < 512) ? ph_b[r - 256] : th_b[r - 512];
  }
}

__global__ __launch_bounds__(256) void cvt_M(const float* __restrict__ Mf,
                                             ushort_t* __restrict__ MT)
{
  int i = blockIdx.x * 256 + threadIdx.x;   // 16*256*256
  const int SL = 1048576;
  float s = 0.f;
#pragma unroll
  for (int k = 0; k < 5; ++k) s += Mf[(size_t)k * SL + i];
  MT[i] = f2b(s * (1.0f / 3136.0f));
}

extern "C" void kernel_launch(void* const* d_in, const int* in_sizes, int n_in,
                              void* d_out, int out_size, void* d_ws, size_t ws_size,
                              hipStream_t stream) {
  const float* x    = (const float*)d_in[0];
  const float* g_w  = (const float*)d_in[1];
  const float* g_b  = (const float*)d_in[2];
  const float* th_w = (const float*)d_in[3];
  const float* th_b = (const float*)d_in[4];
  const float* ph_w = (const float*)d_in[5];
  const float* ph_b = (const float*)d_in[6];
  const float* W_w  = (const float*)d_in[7];
  const float* W_b  = (const float*)d_in[8];

  char* ws = (char*)d_ws;
  ushort_t* xb   = (ushort_t*)(ws + 0);            // 52,428,800 (dead after G1)
  float*    Mf2  = (float*)(ws + 0);               // 20,971,520 (aliases xb)
  ushort_t* MT2  = (ushort_t*)(ws + 41943040);     // 2,097,152 (aliases xb tail)
  ushort_t* U    = (ushort_t*)(ws + 44040192);     // 4,194,304 (aliases xb tail)
  ushort_t* thT  = (ushort_t*)(ws + 52428800);     // 25,690,112
  ushort_t* P    = (ushort_t*)(ws + 78118912);     // 52,428,800
  ushort_t* W3   = (ushort_t*)(ws + 130547712);    // 786,432
  ushort_t* Wwb  = (ushort_t*)(ws + 131334144);    // 262,144
  float*    bias3 = (float*)(ws + 131596288);      // 3,072

  prep_weights<<<2052, 256, 0, stream>>>(g_w, ph_w, th_w, W_w, g_b, ph_b, th_b,
                                         W3, Wwb, bias3);
  transp_x<<<dim3(49, 8, 16), 256, 0, stream>>>(x, xb);

  // G1: P(g,ph) + thT = W3 .NT xb (+bias3)   M=768, N=3328-tiled, K=512
  g1_8phase<<<dim3(3, 13, 16), 512, 0, stream>>>(W3, xb, P, thT, bias3);
  // G2: Mf2 partials = ph .NT g   split-K 5x640
  gemm64<2><<<dim3(2, 2, 80), 256, 0, stream>>>(P, nullptr, Mf2);
  cvt_M<<<4096, 256, 0, stream>>>(Mf2, MT2);
  // GU: U = Wwb .NT MT2            M=512, N=256, K=256
  gemm64<6><<<dim3(4, 2, 16), 256, 0, stream>>>(Wwb, MT2, U);
  // G4: out = U .NT thT + x + W_b  M=512, N=3328-tiled, K=256 (8-phase, nkt=4)
  g4_8phase<<<dim3(2, 13, 16), 512, 0, stream>>>(U, thT, (float*)d_out, x, W_b);
}

// Round 11
// 161.634 us; speedup vs baseline: 1.7618x; 1.0978x over previous
//
#include <hip/hip_runtime.h>
#include <stdint.h>

// ---------------------------------------------------------------------------
// NonLocalBlock2D  B=16, C=512, I=256, N=3136.  (R7 pipeline, all GEMMs on the
// 128^2 gemm64 chassis: 64KiB LDS -> 2 blocks/CU so epilogue/prologue of one
// block overlaps the K-loop of the co-resident one.)
//   xb  [b][3136][512] = x^T bf16
//   G1 (MODE1): m-tiles 0-3 -> P[b][512][3136] (g,ph) ; m-tiles 4-5 -> thT
//               (transposed store, [b][3200 alloc][256], rows>=3136 unwritten)
//   G2 (MODE2): Mf2 partials = ph .NT g, split-K 7x448
//   cvt: MT2 = (1/N) sum partials
//   GU (MODE6): U = Ww .NT MT2
//   G4 (MODE4): out = U .NT thT + x + W_b  (f32 LDS-roundtrip epilogue)
// Workspace:
//   xb  @ 0          : 51,380,224  (dead after G1)
//     Mf2 @ 0          : 29,360,128 (alias)
//     MT2 @ 29,360,128 :  2,097,152 (alias)
//     U   @ 31,457,280 :  4,194,304 (alias)
//   P   @ 51,380,224 : 51,380,224  (dead after G2)
//   thT @ 102,760,448: 26,214,400  (G4 tail reads spill into W3 - discarded)
//   W3  @ 128,974,848:    786,432
//   Wwb @ 129,761,280:    262,144
//   bias3 @ 130,023,424:    3,072   total ~130 MB
// ---------------------------------------------------------------------------

typedef unsigned short ushort_t;
typedef __attribute__((ext_vector_type(8))) short short8;
typedef __attribute__((ext_vector_type(4))) float f32x4;
typedef __attribute__((ext_vector_type(8))) unsigned short us8;

#define NSP  3136

#define AS1(p) ((const __attribute__((address_space(1))) void*)(p))
#define AS3(p) ((__attribute__((address_space(3))) void*)(p))

__device__ inline ushort_t f2b(float f) {
  union { float f; uint32_t u; } c; c.f = f;
  uint32_t u = c.u;
  uint32_t r = (u + 0x7fffu + ((u >> 16) & 1u)) >> 16;
  return (ushort_t)r;
}

// MODE 1: G1 : A=W3[768][512], B=xb_b, K=512.  C-> P (m0<512) / thT (m0>=512)
// MODE 2: G2 : Mf2 = ph .NT g  (K=3136 split 7x448) f32 partials
// MODE 6: GU : U = Ww .NT MT2  (K=256) bf16
// MODE 4: G4 : out = U .NT thT + x + W_b (K=256) f32
template<int MODE>
__global__ __launch_bounds__(256, 2) void gemm64(
    const ushort_t* __restrict__ Abase,
    const ushort_t* __restrict__ Bbase,
    void* __restrict__ Cbase, void* __restrict__ C2,
    const float* __restrict__ bias,
    const float* __restrict__ xres)
{
  constexpr int TB = 256;
  constexpr int CH = TB / 8;           // 32 rows per stage chunk

  const int nwg = gridDim.x * gridDim.y * gridDim.z;
  int flat = blockIdx.x + gridDim.x * (blockIdx.y + gridDim.y * blockIdx.z);
  const int q = nwg >> 3;
  int swz = (flat & 7) * q + (flat >> 3);
  const int bx = swz % gridDim.x; int tmp = swz / gridDim.x;
  const int by = tmp % gridDim.y;
  const int bz = tmp / gridDim.y;

  int b = bz, kc = 0, kbeg = 0, kend, lda, ldb;
  const ushort_t *A, *B;
  if constexpr (MODE == 1) {
    A = Abase;                                   // W3
    B = Bbase + (size_t)b * 1605632;             // xb_b (3136x512)
    lda = 512; ldb = 512; kend = 512;
  } else if constexpr (MODE == 2) {
    b = bz & 15; kc = bz >> 4;
    A = Abase + (size_t)b * 1605632 + 802816;    // ph rows of P_b
    B = Abase + (size_t)b * 1605632;             // g rows
    lda = NSP; ldb = NSP; kbeg = kc * 448; kend = kbeg + 448;
  } else if constexpr (MODE == 6) {
    A = Abase; lda = 256;                        // Wwb [512][256]
    B = Bbase + (size_t)b * 65536; ldb = 256;    // MT2_b
    kend = 256;
  } else {
    A = Abase + (size_t)b * 131072; lda = 256;   // U_b [512][256]
    B = Bbase + (size_t)b * 819200; ldb = 256;   // thT_b ([3200][256] alloc)
    kend = 256;
  }

  const int m0 = bx * 128;
  const int n0 = by * 128;
  const int tid = threadIdx.x;
  const int lane = tid & 63;
  const int wid = tid >> 6;
  const int wm = wid >> 1, wn = wid & 1;
  const int fr = lane & 15;
  const int fk = lane >> 4;

  __shared__ __align__(16) ushort_t SMu[32768];   // 64 KiB: As | Bs, reused by epilogues
  ushort_t (*As)[8192] = (ushort_t(*)[8192])(SMu);
  ushort_t (*Bs)[8192] = (ushort_t(*)[8192])(SMu + 16384);

  f32x4 acc[4][4];
#pragma unroll
  for (int i = 0; i < 4; ++i)
#pragma unroll
    for (int j = 0; j < 4; ++j) acc[i][j] = f32x4{0.f, 0.f, 0.f, 0.f};

  const int srow = tid >> 3;
  const int lsl = (tid & 7) ^ (srow & 7);
  const ushort_t* pa = A + (size_t)(m0 + srow) * lda + kbeg + lsl * 8;
  const ushort_t* pb = B + (size_t)(n0 + srow) * ldb + kbeg + lsl * 8;

#define STAGE(bufi) do {                                                              \
    __builtin_amdgcn_global_load_lds(AS1(pa),                    AS3(&As[bufi][tid * 8]), 16, 0, 0); \
    __builtin_amdgcn_global_load_lds(AS1(pa + (size_t)CH * lda), AS3(&As[bufi][TB * 8 + tid * 8]), 16, 0, 0); \
    __builtin_amdgcn_global_load_lds(AS1(pa + (size_t)2 * CH * lda), AS3(&As[bufi][2 * TB * 8 + tid * 8]), 16, 0, 0); \
    __builtin_amdgcn_global_load_lds(AS1(pa + (size_t)3 * CH * lda), AS3(&As[bufi][3 * TB * 8 + tid * 8]), 16, 0, 0); \
    __builtin_amdgcn_global_load_lds(AS1(pb),                    AS3(&Bs[bufi][tid * 8]), 16, 0, 0); \
    __builtin_amdgcn_global_load_lds(AS1(pb + (size_t)CH * ldb), AS3(&Bs[bufi][TB * 8 + tid * 8]), 16, 0, 0); \
    __builtin_amdgcn_global_load_lds(AS1(pb + (size_t)2 * CH * ldb), AS3(&Bs[bufi][2 * TB * 8 + tid * 8]), 16, 0, 0); \
    __builtin_amdgcn_global_load_lds(AS1(pb + (size_t)3 * CH * ldb), AS3(&Bs[bufi][3 * TB * 8 + tid * 8]), 16, 0, 0); \
    pa += 64; pb += 64;                                                               \
  } while (0)

  const int sw = fr & 7;
  const int s0 = ((0 | fk) ^ sw) * 8;
  const int s1 = ((4 | fk) ^ sw) * 8;
  const int arow = (wm * 64 + fr) * 64;
  const int brow = (wn * 64 + fr) * 64;

  asm volatile("s_waitcnt vmcnt(0)" ::: "memory");
  STAGE(0);

  const int nkt = (kend - kbeg) >> 6;
  for (int t = 0; t < nkt; ++t) {
    const int cur = t & 1;
    if (t + 1 < nkt) {
      STAGE(cur ^ 1);
      asm volatile("s_waitcnt vmcnt(8)" ::: "memory");
    } else {
      asm volatile("s_waitcnt vmcnt(0)" ::: "memory");
    }
    __builtin_amdgcn_s_barrier();
    __builtin_amdgcn_sched_barrier(0);

    short8 bf[4][2];
#pragma unroll
    for (int n = 0; n < 4; ++n) {
      bf[n][0] = *reinterpret_cast<const short8*>(&Bs[cur][brow + n * 1024 + s0]);
      bf[n][1] = *reinterpret_cast<const short8*>(&Bs[cur][brow + n * 1024 + s1]);
    }
    short8 af[4][2];
#pragma unroll
    for (int m = 0; m < 4; ++m) {
      af[m][0] = *reinterpret_cast<const short8*>(&As[cur][arow + m * 1024 + s0]);
      af[m][1] = *reinterpret_cast<const short8*>(&As[cur][arow + m * 1024 + s1]);
    }
    __builtin_amdgcn_s_setprio(1);
#pragma unroll
    for (int m = 0; m < 4; ++m)
#pragma unroll
      for (int n = 0; n < 4; ++n) {
        acc[m][n] = __builtin_amdgcn_mfma_f32_16x16x32_bf16(af[m][0], bf[n][0], acc[m][n], 0, 0, 0);
        acc[m][n] = __builtin_amdgcn_mfma_f32_16x16x32_bf16(af[m][1], bf[n][1], acc[m][n], 0, 0, 0);
      }
    __builtin_amdgcn_s_setprio(0);
    __builtin_amdgcn_s_barrier();
  }
#undef STAGE

  // ===================== epilogues =====================
  if constexpr (MODE == 1) {
    ushort_t* SMe = SMu;              // [128][132] ushort = 33,792 B
    if (m0 < 512) {
      // P rows (g,ph): single-pass stage, coalesced us8 out
#pragma unroll
      for (int m = 0; m < 4; ++m)
#pragma unroll
        for (int n = 0; n < 4; ++n) {
          int col = wn * 64 + n * 16 + fr;
#pragma unroll
          for (int r = 0; r < 4; ++r) {
            int row = wm * 64 + m * 16 + fk * 4 + r;
            SMe[row * 132 + col] = f2b(acc[m][n][r] + bias[m0 + row]);
          }
        }
      __builtin_amdgcn_s_barrier();
      ushort_t* P = (ushort_t*)Cbase;
#pragma unroll
      for (int it = 0; it < 8; ++it) {
        int idx = it * 256 + tid;
        int row = idx >> 4, ch = idx & 15;
        int gcol = n0 + ch * 8;
        if (gcol < NSP)
          *reinterpret_cast<us8*>(
              &P[(size_t)b * 512 * NSP + (size_t)(m0 + row) * NSP + gcol]) =
              *reinterpret_cast<const us8*>(&SMe[row * 132 + ch * 8]);
      }
    } else {
      // th rows -> thT transposed: SMe[n_local][j_local]
      const int j0 = m0 - 512;
#pragma unroll
      for (int m = 0; m < 4; ++m)
#pragma unroll
        for (int n = 0; n < 4; ++n) {
          int nl = wn * 64 + n * 16 + fr;
#pragma unroll
          for (int r = 0; r < 4; ++r) {
            int jl = wm * 64 + m * 16 + fk * 4 + r;
            SMe[nl * 132 + jl] = f2b(acc[m][n][r] + bias[512 + j0 + jl]);
          }
        }
      __builtin_amdgcn_s_barrier();
      ushort_t* thT = (ushort_t*)C2;
#pragma unroll
      for (int it = 0; it < 8; ++it) {
        int idx = it * 256 + tid;
        int row = idx >> 4, ch = idx & 15;
        int gn = n0 + row;
        if (gn < NSP)
          *reinterpret_cast<us8*>(
              &thT[(size_t)b * 819200 + (size_t)gn * 256 + j0 + ch * 8]) =
              *reinterpret_cast<const us8*>(&SMe[row * 132 + ch * 8]);
      }
    }
  } else if constexpr (MODE == 2) {
    float* Mf = (float*)Cbase;
#pragma unroll
    for (int m = 0; m < 4; ++m)
#pragma unroll
      for (int n = 0; n < 4; ++n) {
        int gcol = n0 + wn * 64 + n * 16 + fr;
#pragma unroll
        for (int r = 0; r < 4; ++r) {
          int grow = m0 + wm * 64 + m * 16 + fk * 4 + r;
          Mf[((size_t)kc * 16 + b) * 65536 + grow * 256 + gcol] = acc[m][n][r];
        }
      }
  } else if constexpr (MODE == 6) {
    ushort_t* U = (ushort_t*)Cbase;
#pragma unroll
    for (int m = 0; m < 4; ++m)
#pragma unroll
      for (int n = 0; n < 4; ++n) {
        int gcol = n0 + wn * 64 + n * 16 + fr;
#pragma unroll
        for (int r = 0; r < 4; ++r) {
          int grow = m0 + wm * 64 + m * 16 + fk * 4 + r;
          U[(size_t)b * 131072 + grow * 256 + gcol] = f2b(acc[m][n][r]);
        }
      }
  } else {
    // -------- MODE 4: LDS-roundtrip f32 epilogue, float4-coalesced --------
    float* out = (float*)Cbase;
    float* SMf = (float*)SMu;         // 64 rows x 132 floats
#pragma unroll
    for (int p = 0; p < 2; ++p) {
      if (wm == p) {
#pragma unroll
        for (int m = 0; m < 4; ++m)
#pragma unroll
          for (int n = 0; n < 4; ++n) {
            int col = wn * 64 + n * 16 + fr;
#pragma unroll
            for (int r = 0; r < 4; ++r)
              SMf[(m * 16 + fk * 4 + r) * 132 + col] = acc[m][n][r];
          }
      }
      __builtin_amdgcn_s_barrier();
#pragma unroll
      for (int it = 0; it < 8; ++it) {
        int idx = it * 256 + tid;
        int row = idx >> 5, ch = idx & 31;
        int gcol = n0 + ch * 4;
        if (gcol < NSP) {
          int grow = m0 + p * 64 + row;
          size_t o = ((size_t)b * 512 + grow) * NSP + gcol;
          f32x4 v = *reinterpret_cast<const f32x4*>(&SMf[row * 132 + ch * 4]);
          f32x4 xr = *reinterpret_cast<const f32x4*>(&xres[o]);
          float bi = bias[grow];
          f32x4 ov = {v[0] + bi + xr[0], v[1] + bi + xr[1],
                      v[2] + bi + xr[2], v[3] + bi + xr[3]};
          *reinterpret_cast<f32x4*>(&out[o]) = ov;
        }
      }
      __builtin_amdgcn_s_barrier();
    }
  }
}

// x [b][512][3136] f32 -> xb [b][3136][512] bf16
__global__ __launch_bounds__(256) void transp_x(const float* __restrict__ x,
                                                ushort_t* __restrict__ xb)
{
  const int nt = blockIdx.x, ct = blockIdx.y, b = blockIdx.z;
  const int t = threadIdx.x;
  const int n0 = nt * 64, c0 = ct * 64;
  __shared__ float Ls[64 * 65];

  const float* xs = x + (size_t)b * 512 * NSP;
#pragma unroll
  for (int p = 0; p < 4; ++p) {
    int cl = p * 16 + (t >> 4);
    int nl = (t & 15) * 4;
    f32x4 v = *reinterpret_cast<const f32x4*>(&xs[(size_t)(c0 + cl) * NSP + n0 + nl]);
    Ls[cl * 65 + nl + 0] = v[0];
    Ls[cl * 65 + nl + 1] = v[1];
    Ls[cl * 65 + nl + 2] = v[2];
    Ls[cl * 65 + nl + 3] = v[3];
  }
  __syncthreads();
#pragma unroll
  for (int it = 0; it < 2; ++it) {
    int idx = it * 256 + t; int nl = idx >> 3, cc = idx & 7;
    us8 o;
#pragma unroll
    for (int j = 0; j < 8; ++j) o[j] = f2b(Ls[(cc * 8 + j) * 65 + nl]);
    *reinterpret_cast<us8*>(&xb[((size_t)b * NSP + n0 + nl) * 512 + c0 + cc * 8]) = o;
  }
}

__global__ __launch_bounds__(256) void prep_weights(
    const float* __restrict__ g_w, const float* __restrict__ ph_w,
    const float* __restrict__ th_w, const float* __restrict__ W_w,
    const float* __restrict__ g_b, const float* __restrict__ ph_b,
    const float* __restrict__ th_b,
    ushort_t* __restrict__ W3, ushort_t* __restrict__ Wwb,
    float* __restrict__ bias3)
{
  int i = blockIdx.x * 256 + threadIdx.x;
  if (i < 393216) {
    int row = i >> 9, col = i & 511;
    float v = (row < 256) ? g_w[row * 512 + col]
            : (row < 512) ? ph_w[(row - 256) * 512 + col]
                          : th_w[(row - 512) * 512 + col];
    W3[i] = f2b(v);
  } else if (i < 524288) {
    Wwb[i - 393216] = f2b(W_w[i - 393216]);
  } else if (i < 525056) {
    int r = i - 524288;
    bias3[r] = (r < 256) ? g_b[r] : (r < 512) ? ph_b[r - 256] : th_b[r - 512];
  }
}

__global__ __launch_bounds__(256) void cvt_M(const float* __restrict__ Mf,
                                             ushort_t* __restrict__ MT)
{
  int i = blockIdx.x * 256 + threadIdx.x;   // 16*256*256
  const int SL = 1048576;
  float s = 0.f;
#pragma unroll
  for (int k = 0; k < 7; ++k) s += Mf[(size_t)k * SL + i];
  MT[i] = f2b(s * (1.0f / 3136.0f));
}

extern "C" void kernel_launch(void* const* d_in, const int* in_sizes, int n_in,
                              void* d_out, int out_size, void* d_ws, size_t ws_size,
                              hipStream_t stream) {
  const float* x    = (const float*)d_in[0];
  const float* g_w  = (const float*)d_in[1];
  const float* g_b  = (const float*)d_in[2];
  const float* th_w = (const float*)d_in[3];
  const float* th_b = (const float*)d_in[4];
  const float* ph_w = (const float*)d_in[5];
  const float* ph_b = (const float*)d_in[6];
  const float* W_w  = (const float*)d_in[7];
  const float* W_b  = (const float*)d_in[8];

  char* ws = (char*)d_ws;
  ushort_t* xb   = (ushort_t*)(ws + 0);            // 51,380,224 (dead after G1)
  float*    Mf2  = (float*)(ws + 0);               // 29,360,128 (alias xb)
  ushort_t* MT2  = (ushort_t*)(ws + 29360128);     // 2,097,152 (alias xb)
  ushort_t* U    = (ushort_t*)(ws + 31457280);     // 4,194,304 (alias xb)
  ushort_t* P    = (ushort_t*)(ws + 51380224);     // 51,380,224 (dead after G2)
  ushort_t* thT  = (ushort_t*)(ws + 102760448);    // 26,214,400
  ushort_t* W3   = (ushort_t*)(ws + 128974848);    // 786,432
  ushort_t* Wwb  = (ushort_t*)(ws + 129761280);    // 262,144
  float*    bias3 = (float*)(ws + 130023424);      // 3,072

  prep_weights<<<2052, 256, 0, stream>>>(g_w, ph_w, th_w, W_w, g_b, ph_b, th_b,
                                         W3, Wwb, bias3);
  transp_x<<<dim3(49, 8, 16), 256, 0, stream>>>(x, xb);

  // G1: P(g,ph) + thT = W3 .NT xb (+bias3)   M=768, N=3328-tiled, K=512
  gemm64<1><<<dim3(6, 26, 16), 256, 0, stream>>>(W3, xb, P, thT, bias3, nullptr);
  // G2: Mf2 partials = ph .NT g   split-K 7x448
  gemm64<2><<<dim3(2, 2, 112), 256, 0, stream>>>(P, nullptr, Mf2, nullptr, nullptr, nullptr);
  cvt_M<<<4096, 256, 0, stream>>>(Mf2, MT2);
  // GU: U = Wwb .NT MT2            M=512, N=256, K=256
  gemm64<6><<<dim3(4, 2, 16), 256, 0, stream>>>(Wwb, MT2, U, nullptr, nullptr, nullptr);
  // G4: out = U .NT thT + x + W_b  M=512, N=3328-tiled, K=256
  gemm64<4><<<dim3(4, 26, 16), 256, 0, stream>>>(U, thT, d_out, nullptr, W_b, x);
}